// Round 3
// baseline (246.444 us; speedup 1.0000x reference)
//
#include <hip/hip_runtime.h>
#include <cfloat>
#include <cmath>

#define NB 8
#define CC 128
#define HH 45
#define WW 60
#define HWP 2700      // H*W
#define KNN 16
#define H0 360
#define W0 480
#define NT 43         // ceil(2700/64) candidates per lane
#define MROWS 21600   // NB * HWP

typedef __bf16 bf16_8 __attribute__((ext_vector_type(8)));
typedef __bf16 bf16_4 __attribute__((ext_vector_type(4)));
typedef float  f32x4  __attribute__((ext_vector_type(4)));

// ---------------------------------------------------------------------------
// 0) Fused setup: transpose+bf16-cast (2720 blk) | median pool (16200 blk) |
//    weight fragment prep (1408 blk) | pad halo zero (496 blk)
// ---------------------------------------------------------------------------
template <int K>
__device__ __forceinline__ void wfrag_body(const float* __restrict__ Wt,
                                           __bf16* __restrict__ wf, int bx, int tid) {
    int t = bx * 256 + tid;
    int j = t & 7;
    int lane = (t >> 3) & 63;
    int nt = (t >> 9) & 7;
    int kc = t >> 12;
    int oc = nt * 16 + (lane & 15);
    int k = kc * 32 + (lane >> 4) * 8 + j;
    wf[t] = (__bf16)Wt[(size_t)oc * K + k];
}

__global__ void __launch_bounds__(256) setup_all(
    const float* __restrict__ cnn, const float* __restrict__ xy,
    const float* __restrict__ orig,
    const float* __restrict__ g_w0, const float* __restrict__ g_w1,
    const float* __restrict__ q_w, const float* __restrict__ conv_w,
    __bf16* __restrict__ cnn_b, __bf16* __restrict__ pad_in,
    float* __restrict__ proj,
    __bf16* __restrict__ g0f, __bf16* __restrict__ g1f,
    __bf16* __restrict__ qf, __bf16* __restrict__ w_frag) {
    int bx = blockIdx.x;
    int tid = threadIdx.x;
    if (bx < 2720) {
        // ---- transpose (N,128,HW) -> cnn_b + pad_in ch 0..127 ----
        __shared__ float tile[32][33];
        int n = bx / 340;
        int r2 = bx % 340;
        int c0 = (r2 / 85) * 32;
        int p0 = (r2 % 85) * 32;
        int tx = tid & 31, ty = tid >> 5;
        #pragma unroll
        for (int r = 0; r < 32; r += 8) {
            int c = c0 + ty + r, p = p0 + tx;
            tile[ty + r][tx] = (p < HWP) ? cnn[((size_t)n * CC + c) * HWP + p] : 0.f;
        }
        __syncthreads();
        #pragma unroll
        for (int r = 0; r < 32; r += 8) {
            int p = p0 + ty + r, c = c0 + tx;
            if (p < HWP) {
                __bf16 bv = (__bf16)tile[tx][ty + r];
                cnn_b[((size_t)n * HWP + p) * 128 + c] = bv;
                int y = p / WW, x = p % WW;
                pad_in[(((size_t)n * 47 + y + 1) * 68 + (x + 1)) * 256 + c] = bv;
            }
        }
    } else if (bx < 2720 + 16200) {
        // ---- median pool 8x8: bitonic sort, lane 31 = lower median ----
        int w = (bx - 2720) * 4 + (tid >> 6);
        int lane = tid & 63;
        int n = w / (3 * HWP);
        int rem = w % (3 * HWP);
        int c = rem / HWP;
        int b = rem % HWP;
        const float* src = (c < 2) ? (xy + ((size_t)n * 2 + c) * H0 * W0)
                                   : (orig + ((size_t)n * 4 + 3) * H0 * W0);
        int by = b / WW, bxp = b % WW;
        int r = lane >> 3, col = lane & 7;
        float v = src[(by * 8 + r) * W0 + bxp * 8 + col];
        #pragma unroll
        for (int k = 2; k <= 64; k <<= 1) {
            #pragma unroll
            for (int j2 = k >> 1; j2 >= 1; j2 >>= 1) {
                float p = __shfl_xor(v, j2, 64);
                bool dir = (lane & k) == 0;
                bool low = (lane & j2) == 0;
                v = (dir == low) ? fminf(v, p) : fmaxf(v, p);
            }
        }
        if (lane == 31) proj[(size_t)c * (NB * HWP) + (size_t)n * HWP + b] = v;
    } else if (bx < 2720 + 16200 + 1408) {
        int pb = bx - (2720 + 16200);
        if (pb < 64)        wfrag_body<128>(g_w0, g0f, pb, tid);
        else if (pb < 128)  wfrag_body<128>(g_w1, g1f, pb - 64, tid);
        else if (pb < 256)  wfrag_body<256>(q_w, qf, pb - 128, tid);
        else {
            int t = (pb - 256) * 256 + tid;          // 294,912
            int j = t & 7;
            int lane = (t >> 3) & 63;
            int ntile = (t >> 9) & 7;
            int icc = (t >> 12) & 7;
            int tap = t >> 15;
            int oc = ntile * 16 + (lane & 15);
            int ic = icc * 32 + (lane >> 4) * 8 + j;
            w_frag[t] = (__bf16)conv_w[((size_t)oc * 256 + ic) * 9 + tap];
        }
    } else {
        // ---- zero 496 halo cells per image (all 256 ch) ----
        int t = (bx - (2720 + 16200 + 1408)) * 256 + tid;
        int cg = t & 31;
        int s = t >> 5;
        int cell = s % 496;
        int n = s / 496;
        int y, x;
        if (cell < 136) { y = (cell < 68) ? 0 : 46; x = cell % 68; }
        else {
            int rem = cell - 136;
            y = 1 + rem / 8;
            int k = rem % 8;
            x = (k == 0) ? 0 : (60 + k);
        }
        bf16_8 z = {};
        *(bf16_8*)&pad_in[(((size_t)n * 47 + y) * 68 + x) * 256 + cg * 8] = z;
    }
}

// ---------------------------------------------------------------------------
// 5) bf16 GEMM layer (unchanged)
// ---------------------------------------------------------------------------
__device__ __forceinline__ void layer_b(
    const __bf16* __restrict__ src,                // LDS [32][136] bf16
    const __bf16* __restrict__ wf,                 // global fragments
    int wave, int lane, int kc_base, f32x4 acc[2][2]) {
    int quad = lane >> 4, lm = lane & 15;
    const bf16_8* wf8 = (const bf16_8*)wf;
    #pragma unroll
    for (int kc = 0; kc < 4; ++kc) {
        bf16_8 b[2], a[2];
        #pragma unroll
        for (int nt = 0; nt < 2; ++nt)
            b[nt] = *(const bf16_8*)&src[(nt * 16 + lm) * 136 + kc * 32 + quad * 8];
        #pragma unroll
        for (int mt = 0; mt < 2; ++mt)
            a[mt] = wf8[((size_t)(kc_base + kc) * 8 + (wave * 2 + mt)) * 64 + lane];
        #pragma unroll
        for (int mt = 0; mt < 2; ++mt)
            #pragma unroll
            for (int nt = 0; nt < 2; ++nt)
                acc[mt][nt] = __builtin_amdgcn_mfma_f32_16x16x32_bf16(
                    a[mt], b[nt], acc[mt][nt], 0, 0, 0);
    }
}

// ---------------------------------------------------------------------------
// 3+5a) MERGED: KNN (VALU/LDS-bound) overlapped with g-MLP iter 1 (MFMA).
//       KNN: TWO rows per wave, fully inline (round-2's helper-function
//       pointer passing defeated SROA and spilled both bound arrays to
//       scratch: +150MB HBM traffic. Everything is now main-scope locals
//       with constant indices; one packed sdp[43] = (uB<<16)|uA.)
//       LDS: union of knn{pts 43200 + sbufj 2048 + scnt 32} and
//       g{2 x (albuf 8704 + inter 8704)} = 45280 B.
//       NOTE: s = fmaf(-2,r,a) is bit-identical to a - 2.0f*r (2r exact).
// ---------------------------------------------------------------------------
#define GBLK 340
#define KCHUNK 169          // ceil(2700/16) row-chunks per image
__global__ void __launch_bounds__(512, 6) knn_g1(
    const float* __restrict__ proj, int* __restrict__ knn,
    const __bf16* __restrict__ Ain,
    const __bf16* __restrict__ w0f, const float* __restrict__ b0, const float* __restrict__ a0p,
    const __bf16* __restrict__ w1f, const float* __restrict__ b1, const float* __restrict__ a1p,
    __bf16* __restrict__ tgb) {
    __shared__ __align__(16) char smraw[45280];
    int bx = blockIdx.x;
    if (bx >= GBLK) {
        // =================== KNN path (2 rows per wave, inline) ===========
#pragma clang fp contract(off)
        float4* pts = (float4*)smraw;                      // (x,y,z,sq)
        int (*sbufj)[64] = (int(*)[64])(smraw + 43200);
        int* scnt = (int*)(smraw + 43200 + 2048);
        int kb = bx - GBLK;                                // 0..1351
        int n = kb & 7;
        int chunk = kb >> 3;                               // 0..168
        const float* px = proj + (size_t)n * HWP;
        const float* py = proj + (size_t)NB * HWP + (size_t)n * HWP;
        const float* pz = proj + (size_t)2 * NB * HWP + (size_t)n * HWP;
        for (int t = threadIdx.x; t < HWP; t += 512) {
            float x = px[t], y = py[t], z = pz[t];
            float4 p;
            p.x = x; p.y = y; p.z = z;
            p.w = (x * x + y * y) + z * z;                 // mirrors jnp.sum(proj*proj,-1)
            pts[t] = p;
        }
        __syncthreads();

        int wave = threadIdx.x >> 6;
        int lane = threadIdx.x & 63;
        int i0 = chunk * 16 + wave * 2;                    // first row of pair
        if (i0 >= HWP) return;                             // no syncs after this point
        int i1 = i0 + 1;
        bool hasB = (i1 < HWP);
        int i1c = hasB ? i1 : i0;
        float4 pA = pts[i0];
        float4 pB = pts[i1c];
        float xA = pA.x, yA = pA.y, zA = pA.z, sqA = pA.w;
        float xB = pB.x, yB = pB.y, zB = pB.z, sqB = pB.w;

        // ---- Pass A: both rows off one pts[j] read; packed u16 bounds ----
        unsigned int sdp[NT];                              // (uB<<16) | uA
        float mnA = FLT_MAX, mnB = FLT_MAX;
        #pragma unroll
        for (int t = 0; t < NT; ++t) {
            int j = lane + t * 64;
            unsigned int pk = 0xFFFFFFFFu;
            if (j < HWP) {
                float4 pj = pts[j];
                float rA = fmaf(zA, pj.z, fmaf(yA, pj.y, xA * pj.x));
                float sA = fmaf(-2.0f, rA, sqA + pj.w);
                mnA = fminf(mnA, sA);
                unsigned int uA = (__float_as_uint(fmaxf(sA, 0.f)) + 0xFFFFu) >> 16;
                float rB = fmaf(zB, pj.z, fmaf(yB, pj.y, xB * pj.x));
                float sB = fmaf(-2.0f, rB, sqB + pj.w);
                mnB = fminf(mnB, sB);
                unsigned int uB = (__float_as_uint(fmaxf(sB, 0.f)) + 0xFFFFu) >> 16;
                pk = uA | (uB << 16);
            }
            sdp[t] = pk;
        }

        // ---- Dual bitonic sort of 64 lane minima (independent chains) ----
        float vA = mnA, vB = mnB;
        #pragma unroll
        for (int k = 2; k <= 64; k <<= 1) {
            #pragma unroll
            for (int j2 = k >> 1; j2 >= 1; j2 >>= 1) {
                float pA_ = __shfl_xor(vA, j2, 64);
                float pB_ = __shfl_xor(vB, j2, 64);
                bool dir = (lane & k) == 0;
                bool low = (lane & j2) == 0;
                bool mlow = (dir == low);
                vA = mlow ? fminf(vA, pA_) : fmaxf(vA, pA_);
                vB = mlow ? fminf(vB, pB_) : fmaxf(vB, pB_);
            }
        }
        float MsA = __shfl(vA, 15, 64);
        float MsB = __shfl(vB, 15, 64);
        float MtA = (MsA > 0.f) ? (MsA * 1.0000005f + 1e-37f) : 0.0f;
        float MtB = (MsB > 0.f) ? (MsB * 1.0000005f + 1e-37f) : 0.0f;
        unsigned int M16A = __float_as_uint(MtA * 1.009f) >> 16;  // u16 round-up slack
        unsigned int M16B = __float_as_uint(MtB * 1.009f) >> 16;

        // ================= ROW A: compaction + selection =================
        {
            if (lane == 0) scnt[wave] = 0;
            #pragma unroll
            for (int t = 0; t < NT; ++t) {
                if ((sdp[t] & 0xFFFFu) <= M16A) {
                    int slot = atomicAdd(&scnt[wave], 1);
                    if (slot < 64) sbufj[wave][slot] = lane + t * 64;
                }
            }
            int cnt = scnt[wave];
            int myj = 0;
            if (cnt >= KNN && cnt <= 64) {
                unsigned long long key = ~0ull;
                if (lane < cnt) {
                    int j = sbufj[wave][lane];
                    float4 pj = pts[j];
                    float r = fmaf(zA, pj.z, fmaf(yA, pj.y, xA * pj.x));
                    float s = fmaf(-2.0f, r, sqA + pj.w);
                    float d = sqrtf(fmaxf(s, 0.f));
                    key = ((unsigned long long)__float_as_uint(d) << 32) | (unsigned int)j;
                }
                #pragma unroll
                for (int k = 2; k <= 64; k <<= 1) {
                    #pragma unroll
                    for (int j2 = k >> 1; j2 >= 1; j2 >>= 1) {
                        unsigned long long p = __shfl_xor(key, j2, 64);
                        bool dir = (lane & k) == 0;
                        bool low = (lane & j2) == 0;
                        bool keepmin = (dir == low);
                        bool pless = p < key;
                        key = (pless == keepmin) ? p : key;
                    }
                }
                myj = (int)(unsigned int)(key & 0xffffffffull);
            } else {
                float lastd = -FLT_MAX; int lastj = -1;
                #pragma unroll 1
                for (int r = 0; r < KNN; ++r) {
                    float bd = FLT_MAX; int bj = 0x7fffffff;
                    #pragma unroll 1
                    for (int t = 0; t < NT; ++t) {
                        int j = lane + t * 64;
                        if (j < HWP) {
                            float4 pj = pts[j];
                            float rr = fmaf(zA, pj.z, fmaf(yA, pj.y, xA * pj.x));
                            float s = fmaf(-2.0f, rr, sqA + pj.w);
                            float d = sqrtf(fmaxf(s, 0.f));
                            bool gt = (d > lastd) || (d == lastd && j > lastj);
                            bool lt = (d < bd) || (d == bd && j < bj);
                            if (gt && lt) { bd = d; bj = j; }
                        }
                    }
                    float md = bd; int mj = bj;
                    #pragma unroll
                    for (int off = 32; off >= 1; off >>= 1) {
                        float od = __shfl_xor(md, off, 64);
                        int oj = __shfl_xor(mj, off, 64);
                        if (od < md || (od == md && oj < mj)) { md = od; mj = oj; }
                    }
                    if (lane == r) myj = mj;
                    lastd = md; lastj = mj;
                }
            }
            if (lane < KNN)
                knn[((size_t)n * HWP + i0) * KNN + lane] = myj;
        }

        // ================= ROW B: compaction + selection =================
        if (hasB) {
            if (lane == 0) scnt[wave] = 0;
            #pragma unroll
            for (int t = 0; t < NT; ++t) {
                if ((sdp[t] >> 16) <= M16B) {
                    int slot = atomicAdd(&scnt[wave], 1);
                    if (slot < 64) sbufj[wave][slot] = lane + t * 64;
                }
            }
            int cnt = scnt[wave];
            int myj = 0;
            if (cnt >= KNN && cnt <= 64) {
                unsigned long long key = ~0ull;
                if (lane < cnt) {
                    int j = sbufj[wave][lane];
                    float4 pj = pts[j];
                    float r = fmaf(zB, pj.z, fmaf(yB, pj.y, xB * pj.x));
                    float s = fmaf(-2.0f, r, sqB + pj.w);
                    float d = sqrtf(fmaxf(s, 0.f));
                    key = ((unsigned long long)__float_as_uint(d) << 32) | (unsigned int)j;
                }
                #pragma unroll
                for (int k = 2; k <= 64; k <<= 1) {
                    #pragma unroll
                    for (int j2 = k >> 1; j2 >= 1; j2 >>= 1) {
                        unsigned long long p = __shfl_xor(key, j2, 64);
                        bool dir = (lane & k) == 0;
                        bool low = (lane & j2) == 0;
                        bool keepmin = (dir == low);
                        bool pless = p < key;
                        key = (pless == keepmin) ? p : key;
                    }
                }
                myj = (int)(unsigned int)(key & 0xffffffffull);
            } else {
                float lastd = -FLT_MAX; int lastj = -1;
                #pragma unroll 1
                for (int r = 0; r < KNN; ++r) {
                    float bd = FLT_MAX; int bj = 0x7fffffff;
                    #pragma unroll 1
                    for (int t = 0; t < NT; ++t) {
                        int j = lane + t * 64;
                        if (j < HWP) {
                            float4 pj = pts[j];
                            float rr = fmaf(zB, pj.z, fmaf(yB, pj.y, xB * pj.x));
                            float s = fmaf(-2.0f, rr, sqB + pj.w);
                            float d = sqrtf(fmaxf(s, 0.f));
                            bool gt = (d > lastd) || (d == lastd && j > lastj);
                            bool lt = (d < bd) || (d == bd && j < bj);
                            if (gt && lt) { bd = d; bj = j; }
                        }
                    }
                    float md = bd; int mj = bj;
                    #pragma unroll
                    for (int off = 32; off >= 1; off >>= 1) {
                        float od = __shfl_xor(md, off, 64);
                        int oj = __shfl_xor(mj, off, 64);
                        if (od < md || (od == md && oj < mj)) { md = od; mj = oj; }
                    }
                    if (lane == r) myj = mj;
                    lastd = md; lastj = mj;
                }
            }
            if (lane < KNN)
                knn[((size_t)n * HWP + i1) * KNN + lane] = myj;
        }
    } else {
        // =================== g-MLP iter-1 path (2 virtual 256-thr blocks) ====
        int half = threadIdx.x >> 8;                   // 0..1
        int tid = threadIdx.x & 255;
        int vb = bx * 2 + half;                        // 0..679 (old fused_g bx)
        __bf16* sb = (__bf16*)smraw;
        __bf16* albuf = sb + half * (32 * 136);
        __bf16* inter = sb + (2 + half) * (32 * 136);
        int nimg = vb & 7;
        int r0 = (vb >> 3) * 32;
        size_t base = (size_t)nimg * HWP;
        int wave = tid >> 6, lane = tid & 63;
        int quad = lane >> 4, lm = lane & 15;
        #pragma unroll
        for (int t = tid; t < 512; t += 256) {
            int row = t >> 4, c8 = (t & 15) * 8;
            int gr = r0 + row; if (gr >= HWP) gr = HWP - 1;   // clamped (discarded later)
            *(bf16_8*)&albuf[row * 136 + c8] =
                *(const bf16_8*)&Ain[(base + gr) * 128 + c8];
        }
        __syncthreads();
        // layer 0
        {
            f32x4 acc[2][2] = {};
            layer_b(albuf, w0f, wave, lane, 0, acc);
            float alpha = a0p[0];
            #pragma unroll
            for (int mt = 0; mt < 2; ++mt) {
                int oc0 = wave * 32 + mt * 16 + quad * 4;
                float4 bb = *(const float4*)&b0[oc0];
                float bv[4] = {bb.x, bb.y, bb.z, bb.w};
                #pragma unroll
                for (int nt = 0; nt < 2; ++nt) {
                    bf16_4 o;
                    #pragma unroll
                    for (int reg = 0; reg < 4; ++reg) {
                        float vv = acc[mt][nt][reg] + bv[reg];
                        vv = (vv >= 0.f) ? vv : alpha * vv;
                        o[reg] = (__bf16)vv;
                    }
                    *(bf16_4*)&inter[(nt * 16 + lm) * 136 + oc0] = o;
                }
            }
        }
        __syncthreads();
        // layer 1
        {
            f32x4 acc[2][2] = {};
            layer_b(inter, w1f, wave, lane, 0, acc);
            float alpha = a1p[0];
            #pragma unroll
            for (int mt = 0; mt < 2; ++mt) {
                int oc0 = wave * 32 + mt * 16 + quad * 4;
                float4 bb = *(const float4*)&b1[oc0];
                float bv[4] = {bb.x, bb.y, bb.z, bb.w};
                #pragma unroll
                for (int nt = 0; nt < 2; ++nt) {
                    bf16_4 o;
                    #pragma unroll
                    for (int reg = 0; reg < 4; ++reg) {
                        float vv = acc[mt][nt][reg] + bv[reg];
                        vv = (vv >= 0.f) ? vv : alpha * vv;
                        o[reg] = (__bf16)vv;
                    }
                    int grow = r0 + nt * 16 + lm;
                    if (grow < HWP)
                        *(bf16_4*)&tgb[(base + grow) * 128 + oc0] = o;
                }
            }
        }
    }
}

// ---------------------------------------------------------------------------
// 5b') FUSED q(iter1) + g-MLP(iter2): block b's q output rows 32b..32b+31 are
//      exactly what g(iter2) block b consumes -> keep them in LDS. Writes
//      h_b (for q iter2 Ain) and tgb2 (fresh buffer: gather reads of tgb_in
//      race with in-place writes otherwise). Bit-exact with the old pipeline.
// ---------------------------------------------------------------------------
__global__ void __launch_bounds__(256) fused_qg(
    const __bf16* __restrict__ Ain, const __bf16* __restrict__ tgb_in,
    const int* __restrict__ knn_idx,
    const __bf16* __restrict__ qf, const float* __restrict__ qb, const float* __restrict__ qap,
    const __bf16* __restrict__ w0f, const float* __restrict__ b0, const float* __restrict__ a0p,
    const __bf16* __restrict__ w1f, const float* __restrict__ b1, const float* __restrict__ a1p,
    __bf16* __restrict__ h_out, __bf16* __restrict__ tgb_out) {
    __shared__ __bf16 hlds[32 * 136];
    __shared__ __bf16 mlds[32 * 136];
    int bx = blockIdx.x;
    int nimg = bx & 7;
    int r0 = (bx >> 3) * 32;
    size_t base = (size_t)nimg * HWP;
    int tid = threadIdx.x;
    int wave = tid >> 6, lane = tid & 63;
    int quad = lane >> 4, lm = lane & 15;
    #pragma unroll
    for (int t = tid; t < 512; t += 256) {
        int row = t >> 4, c8 = (t & 15) * 8;
        int gr = r0 + row; if (gr >= HWP) gr = HWP - 1;
        *(bf16_8*)&hlds[row * 136 + c8] =
            *(const bf16_8*)&Ain[(base + gr) * 128 + c8];
    }
    {   // gather + mean: thread handles (pix, 16 channels)
        int pix = tid >> 3;
        int oct0 = (tid & 7) * 2;
        int grow = r0 + pix; if (grow >= HWP) grow = HWP - 1;
        const int* kn = knn_idx + (base + grow) * KNN;
        const __bf16* tbase = tgb_in + base * 128;
        float a0[8] = {}, a1[8] = {};
        #pragma unroll
        for (int k = 0; k < KNN; ++k) {
            int j = kn[k];
            const __bf16* srcp = tbase + (size_t)j * 128 + oct0 * 8;
            bf16_8 v0 = *(const bf16_8*)srcp;
            bf16_8 v1 = *(const bf16_8*)(srcp + 8);
            #pragma unroll
            for (int e = 0; e < 8; ++e) { a0[e] += (float)v0[e]; a1[e] += (float)v1[e]; }
        }
        const float s = 1.f / 16.f;
        bf16_8 o0, o1;
        #pragma unroll
        for (int e = 0; e < 8; ++e) { o0[e] = (__bf16)(a0[e] * s); o1[e] = (__bf16)(a1[e] * s); }
        *(bf16_8*)&mlds[pix * 136 + oct0 * 8] = o0;
        *(bf16_8*)&mlds[pix * 136 + oct0 * 8 + 8] = o1;
    }
    __syncthreads();
    // q-GEMM
    {
        f32x4 acc[2][2] = {};
        layer_b(hlds, qf, wave, lane, 0, acc);   // k 0..127 (h part)
        layer_b(mlds, qf, wave, lane, 4, acc);   // k 128..255 (m part)
        __syncthreads();                         // all LDS reads done before overwrite
        float alpha = qap[0];
        #pragma unroll
        for (int mt = 0; mt < 2; ++mt) {
            int oc0 = wave * 32 + mt * 16 + quad * 4;
            float4 bb = *(const float4*)&qb[oc0];
            float bv[4] = {bb.x, bb.y, bb.z, bb.w};
            #pragma unroll
            for (int nt = 0; nt < 2; ++nt) {
                bf16_4 o;
                #pragma unroll
                for (int reg = 0; reg < 4; ++reg) {
                    float vv = acc[mt][nt][reg] + bv[reg];
                    vv = (vv >= 0.f) ? vv : alpha * vv;
                    o[reg] = (__bf16)vv;
                }
                *(bf16_4*)&hlds[(nt * 16 + lm) * 136 + oc0] = o;   // stays resident
                int grow = r0 + nt * 16 + lm;
                if (grow < HWP)
                    *(bf16_4*)&h_out[(base + grow) * 128 + oc0] = o;
            }
        }
    }
    __syncthreads();
    // g layer 0 (hlds -> mlds)
    {
        f32x4 acc[2][2] = {};
        layer_b(hlds, w0f, wave, lane, 0, acc);
        float alpha = a0p[0];
        #pragma unroll
        for (int mt = 0; mt < 2; ++mt) {
            int oc0 = wave * 32 + mt * 16 + quad * 4;
            float4 bb = *(const float4*)&b0[oc0];
            float bv[4] = {bb.x, bb.y, bb.z, bb.w};
            #pragma unroll
            for (int nt = 0; nt < 2; ++nt) {
                bf16_4 o;
                #pragma unroll
                for (int reg = 0; reg < 4; ++reg) {
                    float vv = acc[mt][nt][reg] + bv[reg];
                    vv = (vv >= 0.f) ? vv : alpha * vv;
                    o[reg] = (__bf16)vv;
                }
                *(bf16_4*)&mlds[(nt * 16 + lm) * 136 + oc0] = o;
            }
        }
    }
    __syncthreads();
    // g layer 1 (mlds -> tgb_out)
    {
        f32x4 acc[2][2] = {};
        layer_b(mlds, w1f, wave, lane, 0, acc);
        float alpha = a1p[0];
        #pragma unroll
        for (int mt = 0; mt < 2; ++mt) {
            int oc0 = wave * 32 + mt * 16 + quad * 4;
            float4 bb = *(const float4*)&b1[oc0];
            float bv[4] = {bb.x, bb.y, bb.z, bb.w};
            #pragma unroll
            for (int nt = 0; nt < 2; ++nt) {
                bf16_4 o;
                #pragma unroll
                for (int reg = 0; reg < 4; ++reg) {
                    float vv = acc[mt][nt][reg] + bv[reg];
                    vv = (vv >= 0.f) ? vv : alpha * vv;
                    o[reg] = (__bf16)vv;
                }
                int grow = r0 + nt * 16 + lm;
                if (grow < HWP)
                    *(bf16_4*)&tgb_out[(base + grow) * 128 + oc0] = o;
            }
        }
    }
}

// ---------------------------------------------------------------------------
// 5b) Fused gather-mean + q-GEMM (iteration 2, scatters into pad_in ch 128..255)
// ---------------------------------------------------------------------------
__global__ void __launch_bounds__(256) fused_q(
    const __bf16* __restrict__ Ain, const __bf16* __restrict__ tgb,
    const int* __restrict__ knn_idx,
    const __bf16* __restrict__ qf, const float* __restrict__ qb,
    const float* __restrict__ qap,
    __bf16* __restrict__ out_lin, __bf16* __restrict__ pad_out, int mode) {
    __shared__ __bf16 hlds[32 * 136];
    __shared__ __bf16 mlds[32 * 136];
    int bx = blockIdx.x;
    int nimg = bx & 7;
    int r0 = (bx >> 3) * 32;
    size_t base = (size_t)nimg * HWP;
    int tid = threadIdx.x;
    int wave = tid >> 6, lane = tid & 63;
    int quad = lane >> 4, lm = lane & 15;
    #pragma unroll
    for (int t = tid; t < 512; t += 256) {
        int row = t >> 4, c8 = (t & 15) * 8;
        int gr = r0 + row; if (gr >= HWP) gr = HWP - 1;
        *(bf16_8*)&hlds[row * 136 + c8] =
            *(const bf16_8*)&Ain[(base + gr) * 128 + c8];
    }
    {   // gather + mean: thread handles (pix, 16 channels)
        int pix = tid >> 3;
        int oct0 = (tid & 7) * 2;
        int grow = r0 + pix; if (grow >= HWP) grow = HWP - 1;
        const int* kn = knn_idx + (base + grow) * KNN;
        const __bf16* tbase = tgb + base * 128;
        float a0[8] = {}, a1[8] = {};
        #pragma unroll
        for (int k = 0; k < KNN; ++k) {
            int j = kn[k];
            const __bf16* srcp = tbase + (size_t)j * 128 + oct0 * 8;
            bf16_8 v0 = *(const bf16_8*)srcp;
            bf16_8 v1 = *(const bf16_8*)(srcp + 8);
            #pragma unroll
            for (int e = 0; e < 8; ++e) { a0[e] += (float)v0[e]; a1[e] += (float)v1[e]; }
        }
        const float s = 1.f / 16.f;
        bf16_8 o0, o1;
        #pragma unroll
        for (int e = 0; e < 8; ++e) { o0[e] = (__bf16)(a0[e] * s); o1[e] = (__bf16)(a1[e] * s); }
        *(bf16_8*)&mlds[pix * 136 + oct0 * 8] = o0;
        *(bf16_8*)&mlds[pix * 136 + oct0 * 8 + 8] = o1;
    }
    __syncthreads();
    f32x4 acc[2][2] = {};
    layer_b(hlds, qf, wave, lane, 0, acc);   // k 0..127 (h part)
    layer_b(mlds, qf, wave, lane, 4, acc);   // k 128..255 (m part)
    float alpha = qap[0];
    #pragma unroll
    for (int mt = 0; mt < 2; ++mt) {
        int oc0 = wave * 32 + mt * 16 + quad * 4;
        float4 bb = *(const float4*)&qb[oc0];
        float bv[4] = {bb.x, bb.y, bb.z, bb.w};
        #pragma unroll
        for (int nt = 0; nt < 2; ++nt) {
            bf16_4 o;
            #pragma unroll
            for (int reg = 0; reg < 4; ++reg) {
                float vv = acc[mt][nt][reg] + bv[reg];
                vv = (vv >= 0.f) ? vv : alpha * vv;
                o[reg] = (__bf16)vv;
            }
            int grow = r0 + nt * 16 + lm;
            if (grow < HWP) {
                if (mode == 0) {
                    *(bf16_4*)&out_lin[(base + grow) * 128 + oc0] = o;
                } else {
                    int y = grow / WW, x = grow % WW;
                    *(bf16_4*)&pad_out[(((size_t)nimg * 47 + y + 1) * 68 + (x + 1)) * 256 + 128 + oc0] = o;
                }
            }
        }
    }
}

// ---------------------------------------------------------------------------
// 6) Conv 3x3 MFMA, XCD-swizzled flat grid (720): image = blockIdx&7.
// ---------------------------------------------------------------------------
__global__ void __launch_bounds__(256) conv_mfma(
    const __bf16* __restrict__ pad_in,   // (N,47,68,256)
    const __bf16* __restrict__ w_frag,   // fragment-ordered weights
    const float* __restrict__ bias,
    float* __restrict__ out) {           // (N,128,45,60)
    __shared__ __bf16 alds[3 * 66 * 72];         // [dy][px 0..65][ic 0..63], stride 72
    int bx = blockIdx.x;
    int n = bx & 7;
    int rest = bx >> 3;                  // 0..89
    int y = rest % HH;
    int oh = rest / HH;
    int tid = threadIdx.x;
    int wave = tid >> 6, lane = tid & 63;
    int wm = wave & 1, wq = wave >> 1;
    int quad = lane >> 4, lm = lane & 15;

    f32x4 acc[2][2] = {};
    const bf16_8* wf = (const bf16_8*)w_frag;

    for (int c64 = 0; c64 < 4; ++c64) {
        __syncthreads();
        for (int t = tid; t < 1584; t += 256) {  // 3*66*8 x 16B
            int cq = t & 7;
            int xp = (t >> 3) % 66;
            int dy = (t >> 3) / 66;
            size_t src = (((size_t)n * 47 + (y + dy)) * 68 + xp) * 256 + c64 * 64 + cq * 8;
            *(bf16_8*)&alds[(dy * 66 + xp) * 72 + cq * 8] = *(const bf16_8*)&pad_in[src];
        }
        __syncthreads();
        #pragma unroll
        for (int tap = 0; tap < 9; ++tap) {
            int ky = tap / 3, kx = tap % 3;
            #pragma unroll
            for (int h = 0; h < 2; ++h) {
                int icc = c64 * 2 + h;
                bf16_8 b[2], a[2];
                #pragma unroll
                for (int nt = 0; nt < 2; ++nt)
                    b[nt] = wf[(((tap * 8 + icc) * 8) + (oh * 4 + wq * 2 + nt)) * 64 + lane];
                #pragma unroll
                for (int mt = 0; mt < 2; ++mt)
                    a[mt] = *(const bf16_8*)&alds[(ky * 66 + (wm * 32 + mt * 16 + lm + kx)) * 72
                                                  + h * 32 + quad * 8];
                #pragma unroll
                for (int mt = 0; mt < 2; ++mt)
                    #pragma unroll
                    for (int nt = 0; nt < 2; ++nt)
                        acc[mt][nt] = __builtin_amdgcn_mfma_f32_16x16x32_bf16(
                            a[mt], b[nt], acc[mt][nt], 0, 0, 0);
            }
        }
    }
    #pragma unroll
    for (int mt = 0; mt < 2; ++mt) {
        int x0 = wm * 32 + mt * 16 + quad * 4;
        if (x0 >= WW) continue;
        #pragma unroll
        for (int nt = 0; nt < 2; ++nt) {
            int oc = (oh * 4 + wq * 2 + nt) * 16 + lm;
            float bb = bias[oc];
            f32x4 v = acc[mt][nt];
            v[0] += bb; v[1] += bb; v[2] += bb; v[3] += bb;
            *(f32x4*)&out[(((size_t)n * 128 + oc) * HH + y) * WW + x0] = v;
        }
    }
}

// ---------------------------------------------------------------------------
extern "C" void kernel_launch(void* const* d_in, const int* in_sizes, int n_in,
                              void* d_out, int out_size, void* d_ws, size_t ws_size,
                              hipStream_t stream) {
    const float* cnn    = (const float*)d_in[0];
    const float* orig   = (const float*)d_in[1];
    const float* xy     = (const float*)d_in[2];
    const float* g_w0   = (const float*)d_in[3];
    const float* g_b0   = (const float*)d_in[4];
    const float* g_a0   = (const float*)d_in[5];
    const float* g_w1   = (const float*)d_in[6];
    const float* g_b1   = (const float*)d_in[7];
    const float* g_a1   = (const float*)d_in[8];
    const float* q_w    = (const float*)d_in[9];
    const float* q_b    = (const float*)d_in[10];
    const float* q_a    = (const float*)d_in[11];
    const float* conv_w = (const float*)d_in[12];
    const float* conv_b = (const float*)d_in[13];
    float* out = (float*)d_out;

    float* ws = (float*)d_ws;
    const size_t SB = (size_t)MROWS * 128;      // bf16 activation plane count
    __bf16* cnn_b  = (__bf16*)ws;               // SB bf16
    __bf16* h_b    = cnn_b + SB;
    __bf16* tgb    = h_b + SB;
    float*  proj   = (float*)(tgb + SB);        // 64,800 fl
    int*    knn_i  = (int*)(proj + 64800);      // 345,600 int
    __bf16* g0f    = (__bf16*)(knn_i + (size_t)MROWS * KNN);
    __bf16* g1f    = g0f + 16384;
    __bf16* qf     = g1f + 16384;               // 32,768 bf16
    __bf16* w_frag = qf + 32768;                // 294,912 bf16
    __bf16* pad_in = w_frag + 294912;           // 6,545,408 bf16
    __bf16* tgb2   = pad_in + (size_t)NB * 47 * 68 * 256;   // SB bf16 (iter-2 tgb)

    setup_all<<<2720 + 16200 + 1408 + 496, 256, 0, stream>>>(
        cnn, xy, orig, g_w0, g_w1, q_w, conv_w,
        cnn_b, pad_in, proj, g0f, g1f, qf, w_frag);

    // KNN (2 rows/wave, VALU) overlapped with g-MLP iteration 1 (MFMA)
    knn_g1<<<GBLK + NB * KCHUNK, 512, 0, stream>>>(
        proj, knn_i, cnn_b, g0f, g_b0, g_a0, g1f, g_b1, g_a1, tgb);

    // q iteration 1 fused with g iteration 2 (LDS-resident handoff)
    fused_qg<<<680, 256, 0, stream>>>(
        cnn_b, tgb, knn_i, qf, q_b, q_a,
        g0f, g_b0, g_a0, g1f, g_b1, g_a1, h_b, tgb2);

    // q iteration 2 scatters straight into conv staging
    fused_q<<<680, 256, 0, stream>>>(h_b, tgb2, knn_i, qf, q_b, q_a, h_b, pad_in, 1);

    // Conv epilogue
    conv_mfma<<<720, 256, 0, stream>>>(pad_in, w_frag, conv_b, out);
}

// Round 4
// 229.332 us; speedup vs baseline: 1.0746x; 1.0746x over previous
//
#include <hip/hip_runtime.h>
#include <cfloat>
#include <cmath>

#define NB 8
#define CC 128
#define HH 45
#define WW 60
#define HWP 2700      // H*W
#define KNN 16
#define H0 360
#define W0 480
#define NT 43         // ceil(2700/64) candidates per lane
#define NT0 22        // first chunk (promotable alloca size, proven in round 1)
#define NT1 21        // second chunk
#define MROWS 21600   // NB * HWP

typedef __bf16 bf16_8 __attribute__((ext_vector_type(8)));
typedef __bf16 bf16_4 __attribute__((ext_vector_type(4)));
typedef float  f32x4  __attribute__((ext_vector_type(4)));

// ---------------------------------------------------------------------------
// 0) Fused setup: transpose+bf16-cast (2720 blk) | median pool (16200 blk) |
//    weight fragment prep (1408 blk) | pad halo zero (496 blk)
// ---------------------------------------------------------------------------
template <int K>
__device__ __forceinline__ void wfrag_body(const float* __restrict__ Wt,
                                           __bf16* __restrict__ wf, int bx, int tid) {
    int t = bx * 256 + tid;
    int j = t & 7;
    int lane = (t >> 3) & 63;
    int nt = (t >> 9) & 7;
    int kc = t >> 12;
    int oc = nt * 16 + (lane & 15);
    int k = kc * 32 + (lane >> 4) * 8 + j;
    wf[t] = (__bf16)Wt[(size_t)oc * K + k];
}

__global__ void __launch_bounds__(256) setup_all(
    const float* __restrict__ cnn, const float* __restrict__ xy,
    const float* __restrict__ orig,
    const float* __restrict__ g_w0, const float* __restrict__ g_w1,
    const float* __restrict__ q_w, const float* __restrict__ conv_w,
    __bf16* __restrict__ cnn_b, __bf16* __restrict__ pad_in,
    float* __restrict__ proj,
    __bf16* __restrict__ g0f, __bf16* __restrict__ g1f,
    __bf16* __restrict__ qf, __bf16* __restrict__ w_frag) {
    int bx = blockIdx.x;
    int tid = threadIdx.x;
    if (bx < 2720) {
        // ---- transpose (N,128,HW) -> cnn_b + pad_in ch 0..127 ----
        __shared__ float tile[32][33];
        int n = bx / 340;
        int r2 = bx % 340;
        int c0 = (r2 / 85) * 32;
        int p0 = (r2 % 85) * 32;
        int tx = tid & 31, ty = tid >> 5;
        #pragma unroll
        for (int r = 0; r < 32; r += 8) {
            int c = c0 + ty + r, p = p0 + tx;
            tile[ty + r][tx] = (p < HWP) ? cnn[((size_t)n * CC + c) * HWP + p] : 0.f;
        }
        __syncthreads();
        #pragma unroll
        for (int r = 0; r < 32; r += 8) {
            int p = p0 + ty + r, c = c0 + tx;
            if (p < HWP) {
                __bf16 bv = (__bf16)tile[tx][ty + r];
                cnn_b[((size_t)n * HWP + p) * 128 + c] = bv;
                int y = p / WW, x = p % WW;
                pad_in[(((size_t)n * 47 + y + 1) * 68 + (x + 1)) * 256 + c] = bv;
            }
        }
    } else if (bx < 2720 + 16200) {
        // ---- median pool 8x8: bitonic sort, lane 31 = lower median ----
        int w = (bx - 2720) * 4 + (tid >> 6);
        int lane = tid & 63;
        int n = w / (3 * HWP);
        int rem = w % (3 * HWP);
        int c = rem / HWP;
        int b = rem % HWP;
        const float* src = (c < 2) ? (xy + ((size_t)n * 2 + c) * H0 * W0)
                                   : (orig + ((size_t)n * 4 + 3) * H0 * W0);
        int by = b / WW, bxp = b % WW;
        int r = lane >> 3, col = lane & 7;
        float v = src[(by * 8 + r) * W0 + bxp * 8 + col];
        #pragma unroll
        for (int k = 2; k <= 64; k <<= 1) {
            #pragma unroll
            for (int j2 = k >> 1; j2 >= 1; j2 >>= 1) {
                float p = __shfl_xor(v, j2, 64);
                bool dir = (lane & k) == 0;
                bool low = (lane & j2) == 0;
                v = (dir == low) ? fminf(v, p) : fmaxf(v, p);
            }
        }
        if (lane == 31) proj[(size_t)c * (NB * HWP) + (size_t)n * HWP + b] = v;
    } else if (bx < 2720 + 16200 + 1408) {
        int pb = bx - (2720 + 16200);
        if (pb < 64)        wfrag_body<128>(g_w0, g0f, pb, tid);
        else if (pb < 128)  wfrag_body<128>(g_w1, g1f, pb - 64, tid);
        else if (pb < 256)  wfrag_body<256>(q_w, qf, pb - 128, tid);
        else {
            int t = (pb - 256) * 256 + tid;          // 294,912
            int j = t & 7;
            int lane = (t >> 3) & 63;
            int ntile = (t >> 9) & 7;
            int icc = (t >> 12) & 7;
            int tap = t >> 15;
            int oc = ntile * 16 + (lane & 15);
            int ic = icc * 32 + (lane >> 4) * 8 + j;
            w_frag[t] = (__bf16)conv_w[((size_t)oc * 256 + ic) * 9 + tap];
        }
    } else {
        // ---- zero 496 halo cells per image (all 256 ch) ----
        int t = (bx - (2720 + 16200 + 1408)) * 256 + tid;
        int cg = t & 31;
        int s = t >> 5;
        int cell = s % 496;
        int n = s / 496;
        int y, x;
        if (cell < 136) { y = (cell < 68) ? 0 : 46; x = cell % 68; }
        else {
            int rem = cell - 136;
            y = 1 + rem / 8;
            int k = rem % 8;
            x = (k == 0) ? 0 : (60 + k);
        }
        bf16_8 z = {};
        *(bf16_8*)&pad_in[(((size_t)n * 47 + y) * 68 + x) * 256 + cg * 8] = z;
    }
}

// ---------------------------------------------------------------------------
// 5) bf16 GEMM layer (unchanged)
// ---------------------------------------------------------------------------
__device__ __forceinline__ void layer_b(
    const __bf16* __restrict__ src,                // LDS [32][136] bf16
    const __bf16* __restrict__ wf,                 // global fragments
    int wave, int lane, int kc_base, f32x4 acc[2][2]) {
    int quad = lane >> 4, lm = lane & 15;
    const bf16_8* wf8 = (const bf16_8*)wf;
    #pragma unroll
    for (int kc = 0; kc < 4; ++kc) {
        bf16_8 b[2], a[2];
        #pragma unroll
        for (int nt = 0; nt < 2; ++nt)
            b[nt] = *(const bf16_8*)&src[(nt * 16 + lm) * 136 + kc * 32 + quad * 8];
        #pragma unroll
        for (int mt = 0; mt < 2; ++mt)
            a[mt] = wf8[((size_t)(kc_base + kc) * 8 + (wave * 2 + mt)) * 64 + lane];
        #pragma unroll
        for (int mt = 0; mt < 2; ++mt)
            #pragma unroll
            for (int nt = 0; nt < 2; ++nt)
                acc[mt][nt] = __builtin_amdgcn_mfma_f32_16x16x32_bf16(
                    a[mt], b[nt], acc[mt][nt], 0, 0, 0);
    }
}

// ---------------------------------------------------------------------------
// 3+5a) MERGED: KNN (VALU/LDS-bound) overlapped with g-MLP iter 1 (MFMA).
//       KNN: TWO rows per wave. Rounds 2/3 spilled the 43-dword bound array
//       (VGPR pinned at 40, +150MB scratch HBM traffic): the AMDGPU
//       promote-alloca heuristic refuses allocas larger than ~half the
//       per-wave VGPR budget (85 at launch_bounds(512,6)). Fix:
//       (a) launch_bounds(512,4) -> budget 128 (floor guarantee only;
//           runtime occupancy stays LDS-limited at 3 blk/CU if alloc <=85);
//       (b) split into sdp0[22]+sdp1[21], each the size proven to promote.
//       LDS: union of knn{pts 43200 + sbufj 2048 + scnt 32} and
//       g{2 x (albuf 8704 + inter 8704)} = 45280 B.
//       NOTE: s = fmaf(-2,r,a) is bit-identical to a - 2.0f*r (2r exact).
// ---------------------------------------------------------------------------
#define GBLK 340
#define KCHUNK 169          // ceil(2700/16) row-chunks per image
__global__ void __launch_bounds__(512, 4) knn_g1(
    const float* __restrict__ proj, int* __restrict__ knn,
    const __bf16* __restrict__ Ain,
    const __bf16* __restrict__ w0f, const float* __restrict__ b0, const float* __restrict__ a0p,
    const __bf16* __restrict__ w1f, const float* __restrict__ b1, const float* __restrict__ a1p,
    __bf16* __restrict__ tgb) {
    __shared__ __align__(16) char smraw[45280];
    int bx = blockIdx.x;
    if (bx >= GBLK) {
        // =================== KNN path (2 rows per wave, inline) ===========
#pragma clang fp contract(off)
        float4* pts = (float4*)smraw;                      // (x,y,z,sq)
        int (*sbufj)[64] = (int(*)[64])(smraw + 43200);
        int* scnt = (int*)(smraw + 43200 + 2048);
        int kb = bx - GBLK;                                // 0..1351
        int n = kb & 7;
        int chunk = kb >> 3;                               // 0..168
        const float* px = proj + (size_t)n * HWP;
        const float* py = proj + (size_t)NB * HWP + (size_t)n * HWP;
        const float* pz = proj + (size_t)2 * NB * HWP + (size_t)n * HWP;
        for (int t = threadIdx.x; t < HWP; t += 512) {
            float x = px[t], y = py[t], z = pz[t];
            float4 p;
            p.x = x; p.y = y; p.z = z;
            p.w = (x * x + y * y) + z * z;                 // mirrors jnp.sum(proj*proj,-1)
            pts[t] = p;
        }
        __syncthreads();

        int wave = threadIdx.x >> 6;
        int lane = threadIdx.x & 63;
        int i0 = chunk * 16 + wave * 2;                    // first row of pair
        if (i0 >= HWP) return;                             // no syncs after this point
        int i1 = i0 + 1;
        bool hasB = (i1 < HWP);
        int i1c = hasB ? i1 : i0;
        float4 pA = pts[i0];
        float4 pB = pts[i1c];
        float xA = pA.x, yA = pA.y, zA = pA.z, sqA = pA.w;
        float xB = pB.x, yB = pB.y, zB = pB.z, sqB = pB.w;

        // ---- Pass A: both rows off one pts[j] read; packed u16 bounds ----
        // Two small allocas (22+21), each individually promotable.
        unsigned int sdp0[NT0];                            // (uB<<16) | uA, t=0..21
        unsigned int sdp1[NT1];                            // t=22..42
        float mnA = FLT_MAX, mnB = FLT_MAX;
        #pragma unroll
        for (int t = 0; t < NT0; ++t) {
            int j = lane + t * 64;
            float4 pj = pts[j];                            // j < 1408 < HWP always
            float rA = fmaf(zA, pj.z, fmaf(yA, pj.y, xA * pj.x));
            float sA = fmaf(-2.0f, rA, sqA + pj.w);
            mnA = fminf(mnA, sA);
            unsigned int uA = (__float_as_uint(fmaxf(sA, 0.f)) + 0xFFFFu) >> 16;
            float rB = fmaf(zB, pj.z, fmaf(yB, pj.y, xB * pj.x));
            float sB = fmaf(-2.0f, rB, sqB + pj.w);
            mnB = fminf(mnB, sB);
            unsigned int uB = (__float_as_uint(fmaxf(sB, 0.f)) + 0xFFFFu) >> 16;
            sdp0[t] = uA | (uB << 16);
        }
        #pragma unroll
        for (int t = 0; t < NT1; ++t) {
            int j = lane + (NT0 + t) * 64;
            unsigned int pk = 0xFFFFFFFFu;
            if (j < HWP) {
                float4 pj = pts[j];
                float rA = fmaf(zA, pj.z, fmaf(yA, pj.y, xA * pj.x));
                float sA = fmaf(-2.0f, rA, sqA + pj.w);
                mnA = fminf(mnA, sA);
                unsigned int uA = (__float_as_uint(fmaxf(sA, 0.f)) + 0xFFFFu) >> 16;
                float rB = fmaf(zB, pj.z, fmaf(yB, pj.y, xB * pj.x));
                float sB = fmaf(-2.0f, rB, sqB + pj.w);
                mnB = fminf(mnB, sB);
                unsigned int uB = (__float_as_uint(fmaxf(sB, 0.f)) + 0xFFFFu) >> 16;
                pk = uA | (uB << 16);
            }
            sdp1[t] = pk;
        }

        // ---- Dual bitonic sort of 64 lane minima (independent chains) ----
        float vA = mnA, vB = mnB;
        #pragma unroll
        for (int k = 2; k <= 64; k <<= 1) {
            #pragma unroll
            for (int j2 = k >> 1; j2 >= 1; j2 >>= 1) {
                float pA_ = __shfl_xor(vA, j2, 64);
                float pB_ = __shfl_xor(vB, j2, 64);
                bool dir = (lane & k) == 0;
                bool low = (lane & j2) == 0;
                bool mlow = (dir == low);
                vA = mlow ? fminf(vA, pA_) : fmaxf(vA, pA_);
                vB = mlow ? fminf(vB, pB_) : fmaxf(vB, pB_);
            }
        }
        float MsA = __shfl(vA, 15, 64);
        float MsB = __shfl(vB, 15, 64);
        float MtA = (MsA > 0.f) ? (MsA * 1.0000005f + 1e-37f) : 0.0f;
        float MtB = (MsB > 0.f) ? (MsB * 1.0000005f + 1e-37f) : 0.0f;
        unsigned int M16A = __float_as_uint(MtA * 1.009f) >> 16;  // u16 round-up slack
        unsigned int M16B = __float_as_uint(MtB * 1.009f) >> 16;

        // ================= ROW A: compaction + selection =================
        {
            if (lane == 0) scnt[wave] = 0;
            #pragma unroll
            for (int t = 0; t < NT0; ++t) {
                if ((sdp0[t] & 0xFFFFu) <= M16A) {
                    int slot = atomicAdd(&scnt[wave], 1);
                    if (slot < 64) sbufj[wave][slot] = lane + t * 64;
                }
            }
            #pragma unroll
            for (int t = 0; t < NT1; ++t) {
                if ((sdp1[t] & 0xFFFFu) <= M16A) {
                    int slot = atomicAdd(&scnt[wave], 1);
                    if (slot < 64) sbufj[wave][slot] = lane + (NT0 + t) * 64;
                }
            }
            int cnt = scnt[wave];
            int myj = 0;
            if (cnt >= KNN && cnt <= 64) {
                unsigned long long key = ~0ull;
                if (lane < cnt) {
                    int j = sbufj[wave][lane];
                    float4 pj = pts[j];
                    float r = fmaf(zA, pj.z, fmaf(yA, pj.y, xA * pj.x));
                    float s = fmaf(-2.0f, r, sqA + pj.w);
                    float d = sqrtf(fmaxf(s, 0.f));
                    key = ((unsigned long long)__float_as_uint(d) << 32) | (unsigned int)j;
                }
                #pragma unroll
                for (int k = 2; k <= 64; k <<= 1) {
                    #pragma unroll
                    for (int j2 = k >> 1; j2 >= 1; j2 >>= 1) {
                        unsigned long long p = __shfl_xor(key, j2, 64);
                        bool dir = (lane & k) == 0;
                        bool low = (lane & j2) == 0;
                        bool keepmin = (dir == low);
                        bool pless = p < key;
                        key = (pless == keepmin) ? p : key;
                    }
                }
                myj = (int)(unsigned int)(key & 0xffffffffull);
            } else {
                float lastd = -FLT_MAX; int lastj = -1;
                #pragma unroll 1
                for (int r = 0; r < KNN; ++r) {
                    float bd = FLT_MAX; int bj = 0x7fffffff;
                    #pragma unroll 1
                    for (int t = 0; t < NT; ++t) {
                        int j = lane + t * 64;
                        if (j < HWP) {
                            float4 pj = pts[j];
                            float rr = fmaf(zA, pj.z, fmaf(yA, pj.y, xA * pj.x));
                            float s = fmaf(-2.0f, rr, sqA + pj.w);
                            float d = sqrtf(fmaxf(s, 0.f));
                            bool gt = (d > lastd) || (d == lastd && j > lastj);
                            bool lt = (d < bd) || (d == bd && j < bj);
                            if (gt && lt) { bd = d; bj = j; }
                        }
                    }
                    float md = bd; int mj = bj;
                    #pragma unroll
                    for (int off = 32; off >= 1; off >>= 1) {
                        float od = __shfl_xor(md, off, 64);
                        int oj = __shfl_xor(mj, off, 64);
                        if (od < md || (od == md && oj < mj)) { md = od; mj = oj; }
                    }
                    if (lane == r) myj = mj;
                    lastd = md; lastj = mj;
                }
            }
            if (lane < KNN)
                knn[((size_t)n * HWP + i0) * KNN + lane] = myj;
        }

        // ================= ROW B: compaction + selection =================
        if (hasB) {
            if (lane == 0) scnt[wave] = 0;
            #pragma unroll
            for (int t = 0; t < NT0; ++t) {
                if ((sdp0[t] >> 16) <= M16B) {
                    int slot = atomicAdd(&scnt[wave], 1);
                    if (slot < 64) sbufj[wave][slot] = lane + t * 64;
                }
            }
            #pragma unroll
            for (int t = 0; t < NT1; ++t) {
                if ((sdp1[t] >> 16) <= M16B) {
                    int slot = atomicAdd(&scnt[wave], 1);
                    if (slot < 64) sbufj[wave][slot] = lane + (NT0 + t) * 64;
                }
            }
            int cnt = scnt[wave];
            int myj = 0;
            if (cnt >= KNN && cnt <= 64) {
                unsigned long long key = ~0ull;
                if (lane < cnt) {
                    int j = sbufj[wave][lane];
                    float4 pj = pts[j];
                    float r = fmaf(zB, pj.z, fmaf(yB, pj.y, xB * pj.x));
                    float s = fmaf(-2.0f, r, sqB + pj.w);
                    float d = sqrtf(fmaxf(s, 0.f));
                    key = ((unsigned long long)__float_as_uint(d) << 32) | (unsigned int)j;
                }
                #pragma unroll
                for (int k = 2; k <= 64; k <<= 1) {
                    #pragma unroll
                    for (int j2 = k >> 1; j2 >= 1; j2 >>= 1) {
                        unsigned long long p = __shfl_xor(key, j2, 64);
                        bool dir = (lane & k) == 0;
                        bool low = (lane & j2) == 0;
                        bool keepmin = (dir == low);
                        bool pless = p < key;
                        key = (pless == keepmin) ? p : key;
                    }
                }
                myj = (int)(unsigned int)(key & 0xffffffffull);
            } else {
                float lastd = -FLT_MAX; int lastj = -1;
                #pragma unroll 1
                for (int r = 0; r < KNN; ++r) {
                    float bd = FLT_MAX; int bj = 0x7fffffff;
                    #pragma unroll 1
                    for (int t = 0; t < NT; ++t) {
                        int j = lane + t * 64;
                        if (j < HWP) {
                            float4 pj = pts[j];
                            float rr = fmaf(zB, pj.z, fmaf(yB, pj.y, xB * pj.x));
                            float s = fmaf(-2.0f, rr, sqB + pj.w);
                            float d = sqrtf(fmaxf(s, 0.f));
                            bool gt = (d > lastd) || (d == lastd && j > lastj);
                            bool lt = (d < bd) || (d == bd && j < bj);
                            if (gt && lt) { bd = d; bj = j; }
                        }
                    }
                    float md = bd; int mj = bj;
                    #pragma unroll
                    for (int off = 32; off >= 1; off >>= 1) {
                        float od = __shfl_xor(md, off, 64);
                        int oj = __shfl_xor(mj, off, 64);
                        if (od < md || (od == md && oj < mj)) { md = od; mj = oj; }
                    }
                    if (lane == r) myj = mj;
                    lastd = md; lastj = mj;
                }
            }
            if (lane < KNN)
                knn[((size_t)n * HWP + i1) * KNN + lane] = myj;
        }
    } else {
        // =================== g-MLP iter-1 path (2 virtual 256-thr blocks) ====
        int half = threadIdx.x >> 8;                   // 0..1
        int tid = threadIdx.x & 255;
        int vb = bx * 2 + half;                        // 0..679 (old fused_g bx)
        __bf16* sb = (__bf16*)smraw;
        __bf16* albuf = sb + half * (32 * 136);
        __bf16* inter = sb + (2 + half) * (32 * 136);
        int nimg = vb & 7;
        int r0 = (vb >> 3) * 32;
        size_t base = (size_t)nimg * HWP;
        int wave = tid >> 6, lane = tid & 63;
        int quad = lane >> 4, lm = lane & 15;
        #pragma unroll
        for (int t = tid; t < 512; t += 256) {
            int row = t >> 4, c8 = (t & 15) * 8;
            int gr = r0 + row; if (gr >= HWP) gr = HWP - 1;   // clamped (discarded later)
            *(bf16_8*)&albuf[row * 136 + c8] =
                *(const bf16_8*)&Ain[(base + gr) * 128 + c8];
        }
        __syncthreads();
        // layer 0
        {
            f32x4 acc[2][2] = {};
            layer_b(albuf, w0f, wave, lane, 0, acc);
            float alpha = a0p[0];
            #pragma unroll
            for (int mt = 0; mt < 2; ++mt) {
                int oc0 = wave * 32 + mt * 16 + quad * 4;
                float4 bb = *(const float4*)&b0[oc0];
                float bv[4] = {bb.x, bb.y, bb.z, bb.w};
                #pragma unroll
                for (int nt = 0; nt < 2; ++nt) {
                    bf16_4 o;
                    #pragma unroll
                    for (int reg = 0; reg < 4; ++reg) {
                        float vv = acc[mt][nt][reg] + bv[reg];
                        vv = (vv >= 0.f) ? vv : alpha * vv;
                        o[reg] = (__bf16)vv;
                    }
                    *(bf16_4*)&inter[(nt * 16 + lm) * 136 + oc0] = o;
                }
            }
        }
        __syncthreads();
        // layer 1
        {
            f32x4 acc[2][2] = {};
            layer_b(inter, w1f, wave, lane, 0, acc);
            float alpha = a1p[0];
            #pragma unroll
            for (int mt = 0; mt < 2; ++mt) {
                int oc0 = wave * 32 + mt * 16 + quad * 4;
                float4 bb = *(const float4*)&b1[oc0];
                float bv[4] = {bb.x, bb.y, bb.z, bb.w};
                #pragma unroll
                for (int nt = 0; nt < 2; ++nt) {
                    bf16_4 o;
                    #pragma unroll
                    for (int reg = 0; reg < 4; ++reg) {
                        float vv = acc[mt][nt][reg] + bv[reg];
                        vv = (vv >= 0.f) ? vv : alpha * vv;
                        o[reg] = (__bf16)vv;
                    }
                    int grow = r0 + nt * 16 + lm;
                    if (grow < HWP)
                        *(bf16_4*)&tgb[(base + grow) * 128 + oc0] = o;
                }
            }
        }
    }
}

// ---------------------------------------------------------------------------
// 5b') FUSED q(iter1) + g-MLP(iter2): block b's q output rows 32b..32b+31 are
//      exactly what g(iter2) block b consumes -> keep them in LDS. Writes
//      h_b (for q iter2 Ain) and tgb2 (fresh buffer: gather reads of tgb_in
//      race with in-place writes otherwise). Bit-exact with the old pipeline.
// ---------------------------------------------------------------------------
__global__ void __launch_bounds__(256) fused_qg(
    const __bf16* __restrict__ Ain, const __bf16* __restrict__ tgb_in,
    const int* __restrict__ knn_idx,
    const __bf16* __restrict__ qf, const float* __restrict__ qb, const float* __restrict__ qap,
    const __bf16* __restrict__ w0f, const float* __restrict__ b0, const float* __restrict__ a0p,
    const __bf16* __restrict__ w1f, const float* __restrict__ b1, const float* __restrict__ a1p,
    __bf16* __restrict__ h_out, __bf16* __restrict__ tgb_out) {
    __shared__ __bf16 hlds[32 * 136];
    __shared__ __bf16 mlds[32 * 136];
    int bx = blockIdx.x;
    int nimg = bx & 7;
    int r0 = (bx >> 3) * 32;
    size_t base = (size_t)nimg * HWP;
    int tid = threadIdx.x;
    int wave = tid >> 6, lane = tid & 63;
    int quad = lane >> 4, lm = lane & 15;
    #pragma unroll
    for (int t = tid; t < 512; t += 256) {
        int row = t >> 4, c8 = (t & 15) * 8;
        int gr = r0 + row; if (gr >= HWP) gr = HWP - 1;
        *(bf16_8*)&hlds[row * 136 + c8] =
            *(const bf16_8*)&Ain[(base + gr) * 128 + c8];
    }
    {   // gather + mean: thread handles (pix, 16 channels)
        int pix = tid >> 3;
        int oct0 = (tid & 7) * 2;
        int grow = r0 + pix; if (grow >= HWP) grow = HWP - 1;
        const int* kn = knn_idx + (base + grow) * KNN;
        const __bf16* tbase = tgb_in + base * 128;
        float a0[8] = {}, a1[8] = {};
        #pragma unroll
        for (int k = 0; k < KNN; ++k) {
            int j = kn[k];
            const __bf16* srcp = tbase + (size_t)j * 128 + oct0 * 8;
            bf16_8 v0 = *(const bf16_8*)srcp;
            bf16_8 v1 = *(const bf16_8*)(srcp + 8);
            #pragma unroll
            for (int e = 0; e < 8; ++e) { a0[e] += (float)v0[e]; a1[e] += (float)v1[e]; }
        }
        const float s = 1.f / 16.f;
        bf16_8 o0, o1;
        #pragma unroll
        for (int e = 0; e < 8; ++e) { o0[e] = (__bf16)(a0[e] * s); o1[e] = (__bf16)(a1[e] * s); }
        *(bf16_8*)&mlds[pix * 136 + oct0 * 8] = o0;
        *(bf16_8*)&mlds[pix * 136 + oct0 * 8 + 8] = o1;
    }
    __syncthreads();
    // q-GEMM
    {
        f32x4 acc[2][2] = {};
        layer_b(hlds, qf, wave, lane, 0, acc);   // k 0..127 (h part)
        layer_b(mlds, qf, wave, lane, 4, acc);   // k 128..255 (m part)
        __syncthreads();                         // all LDS reads done before overwrite
        float alpha = qap[0];
        #pragma unroll
        for (int mt = 0; mt < 2; ++mt) {
            int oc0 = wave * 32 + mt * 16 + quad * 4;
            float4 bb = *(const float4*)&qb[oc0];
            float bv[4] = {bb.x, bb.y, bb.z, bb.w};
            #pragma unroll
            for (int nt = 0; nt < 2; ++nt) {
                bf16_4 o;
                #pragma unroll
                for (int reg = 0; reg < 4; ++reg) {
                    float vv = acc[mt][nt][reg] + bv[reg];
                    vv = (vv >= 0.f) ? vv : alpha * vv;
                    o[reg] = (__bf16)vv;
                }
                *(bf16_4*)&hlds[(nt * 16 + lm) * 136 + oc0] = o;   // stays resident
                int grow = r0 + nt * 16 + lm;
                if (grow < HWP)
                    *(bf16_4*)&h_out[(base + grow) * 128 + oc0] = o;
            }
        }
    }
    __syncthreads();
    // g layer 0 (hlds -> mlds)
    {
        f32x4 acc[2][2] = {};
        layer_b(hlds, w0f, wave, lane, 0, acc);
        float alpha = a0p[0];
        #pragma unroll
        for (int mt = 0; mt < 2; ++mt) {
            int oc0 = wave * 32 + mt * 16 + quad * 4;
            float4 bb = *(const float4*)&b0[oc0];
            float bv[4] = {bb.x, bb.y, bb.z, bb.w};
            #pragma unroll
            for (int nt = 0; nt < 2; ++nt) {
                bf16_4 o;
                #pragma unroll
                for (int reg = 0; reg < 4; ++reg) {
                    float vv = acc[mt][nt][reg] + bv[reg];
                    vv = (vv >= 0.f) ? vv : alpha * vv;
                    o[reg] = (__bf16)vv;
                }
                *(bf16_4*)&mlds[(nt * 16 + lm) * 136 + oc0] = o;
            }
        }
    }
    __syncthreads();
    // g layer 1 (mlds -> tgb_out)
    {
        f32x4 acc[2][2] = {};
        layer_b(mlds, w1f, wave, lane, 0, acc);
        float alpha = a1p[0];
        #pragma unroll
        for (int mt = 0; mt < 2; ++mt) {
            int oc0 = wave * 32 + mt * 16 + quad * 4;
            float4 bb = *(const float4*)&b1[oc0];
            float bv[4] = {bb.x, bb.y, bb.z, bb.w};
            #pragma unroll
            for (int nt = 0; nt < 2; ++nt) {
                bf16_4 o;
                #pragma unroll
                for (int reg = 0; reg < 4; ++reg) {
                    float vv = acc[mt][nt][reg] + bv[reg];
                    vv = (vv >= 0.f) ? vv : alpha * vv;
                    o[reg] = (__bf16)vv;
                }
                int grow = r0 + nt * 16 + lm;
                if (grow < HWP)
                    *(bf16_4*)&tgb_out[(base + grow) * 128 + oc0] = o;
            }
        }
    }
}

// ---------------------------------------------------------------------------
// 5b) Fused gather-mean + q-GEMM (iteration 2, scatters into pad_in ch 128..255)
// ---------------------------------------------------------------------------
__global__ void __launch_bounds__(256) fused_q(
    const __bf16* __restrict__ Ain, const __bf16* __restrict__ tgb,
    const int* __restrict__ knn_idx,
    const __bf16* __restrict__ qf, const float* __restrict__ qb,
    const float* __restrict__ qap,
    __bf16* __restrict__ out_lin, __bf16* __restrict__ pad_out, int mode) {
    __shared__ __bf16 hlds[32 * 136];
    __shared__ __bf16 mlds[32 * 136];
    int bx = blockIdx.x;
    int nimg = bx & 7;
    int r0 = (bx >> 3) * 32;
    size_t base = (size_t)nimg * HWP;
    int tid = threadIdx.x;
    int wave = tid >> 6, lane = tid & 63;
    int quad = lane >> 4, lm = lane & 15;
    #pragma unroll
    for (int t = tid; t < 512; t += 256) {
        int row = t >> 4, c8 = (t & 15) * 8;
        int gr = r0 + row; if (gr >= HWP) gr = HWP - 1;
        *(bf16_8*)&hlds[row * 136 + c8] =
            *(const bf16_8*)&Ain[(base + gr) * 128 + c8];
    }
    {   // gather + mean: thread handles (pix, 16 channels)
        int pix = tid >> 3;
        int oct0 = (tid & 7) * 2;
        int grow = r0 + pix; if (grow >= HWP) grow = HWP - 1;
        const int* kn = knn_idx + (base + grow) * KNN;
        const __bf16* tbase = tgb + base * 128;
        float a0[8] = {}, a1[8] = {};
        #pragma unroll
        for (int k = 0; k < KNN; ++k) {
            int j = kn[k];
            const __bf16* srcp = tbase + (size_t)j * 128 + oct0 * 8;
            bf16_8 v0 = *(const bf16_8*)srcp;
            bf16_8 v1 = *(const bf16_8*)(srcp + 8);
            #pragma unroll
            for (int e = 0; e < 8; ++e) { a0[e] += (float)v0[e]; a1[e] += (float)v1[e]; }
        }
        const float s = 1.f / 16.f;
        bf16_8 o0, o1;
        #pragma unroll
        for (int e = 0; e < 8; ++e) { o0[e] = (__bf16)(a0[e] * s); o1[e] = (__bf16)(a1[e] * s); }
        *(bf16_8*)&mlds[pix * 136 + oct0 * 8] = o0;
        *(bf16_8*)&mlds[pix * 136 + oct0 * 8 + 8] = o1;
    }
    __syncthreads();
    f32x4 acc[2][2] = {};
    layer_b(hlds, qf, wave, lane, 0, acc);   // k 0..127 (h part)
    layer_b(mlds, qf, wave, lane, 4, acc);   // k 128..255 (m part)
    float alpha = qap[0];
    #pragma unroll
    for (int mt = 0; mt < 2; ++mt) {
        int oc0 = wave * 32 + mt * 16 + quad * 4;
        float4 bb = *(const float4*)&qb[oc0];
        float bv[4] = {bb.x, bb.y, bb.z, bb.w};
        #pragma unroll
        for (int nt = 0; nt < 2; ++nt) {
            bf16_4 o;
            #pragma unroll
            for (int reg = 0; reg < 4; ++reg) {
                float vv = acc[mt][nt][reg] + bv[reg];
                vv = (vv >= 0.f) ? vv : alpha * vv;
                o[reg] = (__bf16)vv;
            }
            int grow = r0 + nt * 16 + lm;
            if (grow < HWP) {
                if (mode == 0) {
                    *(bf16_4*)&out_lin[(base + grow) * 128 + oc0] = o;
                } else {
                    int y = grow / WW, x = grow % WW;
                    *(bf16_4*)&pad_out[(((size_t)nimg * 47 + y + 1) * 68 + (x + 1)) * 256 + 128 + oc0] = o;
                }
            }
        }
    }
}

// ---------------------------------------------------------------------------
// 6) Conv 3x3 MFMA, XCD-swizzled flat grid (720): image = blockIdx&7.
// ---------------------------------------------------------------------------
__global__ void __launch_bounds__(256) conv_mfma(
    const __bf16* __restrict__ pad_in,   // (N,47,68,256)
    const __bf16* __restrict__ w_frag,   // fragment-ordered weights
    const float* __restrict__ bias,
    float* __restrict__ out) {           // (N,128,45,60)
    __shared__ __bf16 alds[3 * 66 * 72];         // [dy][px 0..65][ic 0..63], stride 72
    int bx = blockIdx.x;
    int n = bx & 7;
    int rest = bx >> 3;                  // 0..89
    int y = rest % HH;
    int oh = rest / HH;
    int tid = threadIdx.x;
    int wave = tid >> 6, lane = tid & 63;
    int wm = wave & 1, wq = wave >> 1;
    int quad = lane >> 4, lm = lane & 15;

    f32x4 acc[2][2] = {};
    const bf16_8* wf = (const bf16_8*)w_frag;

    for (int c64 = 0; c64 < 4; ++c64) {
        __syncthreads();
        for (int t = tid; t < 1584; t += 256) {  // 3*66*8 x 16B
            int cq = t & 7;
            int xp = (t >> 3) % 66;
            int dy = (t >> 3) / 66;
            size_t src = (((size_t)n * 47 + (y + dy)) * 68 + xp) * 256 + c64 * 64 + cq * 8;
            *(bf16_8*)&alds[(dy * 66 + xp) * 72 + cq * 8] = *(const bf16_8*)&pad_in[src];
        }
        __syncthreads();
        #pragma unroll
        for (int tap = 0; tap < 9; ++tap) {
            int ky = tap / 3, kx = tap % 3;
            #pragma unroll
            for (int h = 0; h < 2; ++h) {
                int icc = c64 * 2 + h;
                bf16_8 b[2], a[2];
                #pragma unroll
                for (int nt = 0; nt < 2; ++nt)
                    b[nt] = wf[(((tap * 8 + icc) * 8) + (oh * 4 + wq * 2 + nt)) * 64 + lane];
                #pragma unroll
                for (int mt = 0; mt < 2; ++mt)
                    a[mt] = *(const bf16_8*)&alds[(ky * 66 + (wm * 32 + mt * 16 + lm + kx)) * 72
                                                  + h * 32 + quad * 8];
                #pragma unroll
                for (int mt = 0; mt < 2; ++mt)
                    #pragma unroll
                    for (int nt = 0; nt < 2; ++nt)
                        acc[mt][nt] = __builtin_amdgcn_mfma_f32_16x16x32_bf16(
                            a[mt], b[nt], acc[mt][nt], 0, 0, 0);
            }
        }
    }
    #pragma unroll
    for (int mt = 0; mt < 2; ++mt) {
        int x0 = wm * 32 + mt * 16 + quad * 4;
        if (x0 >= WW) continue;
        #pragma unroll
        for (int nt = 0; nt < 2; ++nt) {
            int oc = (oh * 4 + wq * 2 + nt) * 16 + lm;
            float bb = bias[oc];
            f32x4 v = acc[mt][nt];
            v[0] += bb; v[1] += bb; v[2] += bb; v[3] += bb;
            *(f32x4*)&out[(((size_t)n * 128 + oc) * HH + y) * WW + x0] = v;
        }
    }
}

// ---------------------------------------------------------------------------
extern "C" void kernel_launch(void* const* d_in, const int* in_sizes, int n_in,
                              void* d_out, int out_size, void* d_ws, size_t ws_size,
                              hipStream_t stream) {
    const float* cnn    = (const float*)d_in[0];
    const float* orig   = (const float*)d_in[1];
    const float* xy     = (const float*)d_in[2];
    const float* g_w0   = (const float*)d_in[3];
    const float* g_b0   = (const float*)d_in[4];
    const float* g_a0   = (const float*)d_in[5];
    const float* g_w1   = (const float*)d_in[6];
    const float* g_b1   = (const float*)d_in[7];
    const float* g_a1   = (const float*)d_in[8];
    const float* q_w    = (const float*)d_in[9];
    const float* q_b    = (const float*)d_in[10];
    const float* q_a    = (const float*)d_in[11];
    const float* conv_w = (const float*)d_in[12];
    const float* conv_b = (const float*)d_in[13];
    float* out = (float*)d_out;

    float* ws = (float*)d_ws;
    const size_t SB = (size_t)MROWS * 128;      // bf16 activation plane count
    __bf16* cnn_b  = (__bf16*)ws;               // SB bf16
    __bf16* h_b    = cnn_b + SB;
    __bf16* tgb    = h_b + SB;
    float*  proj   = (float*)(tgb + SB);        // 64,800 fl
    int*    knn_i  = (int*)(proj + 64800);      // 345,600 int
    __bf16* g0f    = (__bf16*)(knn_i + (size_t)MROWS * KNN);
    __bf16* g1f    = g0f + 16384;
    __bf16* qf     = g1f + 16384;               // 32,768 bf16
    __bf16* w_frag = qf + 32768;                // 294,912 bf16
    __bf16* pad_in = w_frag + 294912;           // 6,545,408 bf16
    __bf16* tgb2   = pad_in + (size_t)NB * 47 * 68 * 256;   // SB bf16 (iter-2 tgb)

    setup_all<<<2720 + 16200 + 1408 + 496, 256, 0, stream>>>(
        cnn, xy, orig, g_w0, g_w1, q_w, conv_w,
        cnn_b, pad_in, proj, g0f, g1f, qf, w_frag);

    // KNN (2 rows/wave, VALU) overlapped with g-MLP iteration 1 (MFMA)
    knn_g1<<<GBLK + NB * KCHUNK, 512, 0, stream>>>(
        proj, knn_i, cnn_b, g0f, g_b0, g_a0, g1f, g_b1, g_a1, tgb);

    // q iteration 1 fused with g iteration 2 (LDS-resident handoff)
    fused_qg<<<680, 256, 0, stream>>>(
        cnn_b, tgb, knn_i, qf, q_b, q_a,
        g0f, g_b0, g_a0, g1f, g_b1, g_a1, h_b, tgb2);

    // q iteration 2 scatters straight into conv staging
    fused_q<<<680, 256, 0, stream>>>(h_b, tgb2, knn_i, qf, q_b, q_a, h_b, pad_in, 1);

    // Conv epilogue
    conv_mfma<<<720, 256, 0, stream>>>(pad_in, w_frag, conv_b, out);
}

// Round 5
// 222.963 us; speedup vs baseline: 1.1053x; 1.0286x over previous
//
#include <hip/hip_runtime.h>
#include <cfloat>
#include <cmath>

#define NB 8
#define CC 128
#define HH 45
#define WW 60
#define HWP 2700      // H*W
#define KNN 16
#define H0 360
#define W0 480
#define NT 43         // ceil(2700/64) candidates per lane
#define MROWS 21600   // NB * HWP

typedef __bf16 bf16_8 __attribute__((ext_vector_type(8)));
typedef __bf16 bf16_4 __attribute__((ext_vector_type(4)));
typedef float  f32x4  __attribute__((ext_vector_type(4)));

// ---------------------------------------------------------------------------
// 0) Fused setup: transpose+bf16-cast (2720 blk) | median pool (16200 blk) |
//    weight fragment prep (1408 blk) | pad halo zero (496 blk)
// ---------------------------------------------------------------------------
template <int K>
__device__ __forceinline__ void wfrag_body(const float* __restrict__ Wt,
                                           __bf16* __restrict__ wf, int bx, int tid) {
    int t = bx * 256 + tid;
    int j = t & 7;
    int lane = (t >> 3) & 63;
    int nt = (t >> 9) & 7;
    int kc = t >> 12;
    int oc = nt * 16 + (lane & 15);
    int k = kc * 32 + (lane >> 4) * 8 + j;
    wf[t] = (__bf16)Wt[(size_t)oc * K + k];
}

__global__ void __launch_bounds__(256) setup_all(
    const float* __restrict__ cnn, const float* __restrict__ xy,
    const float* __restrict__ orig,
    const float* __restrict__ g_w0, const float* __restrict__ g_w1,
    const float* __restrict__ q_w, const float* __restrict__ conv_w,
    __bf16* __restrict__ cnn_b, __bf16* __restrict__ pad_in,
    float* __restrict__ proj,
    __bf16* __restrict__ g0f, __bf16* __restrict__ g1f,
    __bf16* __restrict__ qf, __bf16* __restrict__ w_frag) {
    int bx = blockIdx.x;
    int tid = threadIdx.x;
    if (bx < 2720) {
        // ---- transpose (N,128,HW) -> cnn_b + pad_in ch 0..127 ----
        __shared__ float tile[32][33];
        int n = bx / 340;
        int r2 = bx % 340;
        int c0 = (r2 / 85) * 32;
        int p0 = (r2 % 85) * 32;
        int tx = tid & 31, ty = tid >> 5;
        #pragma unroll
        for (int r = 0; r < 32; r += 8) {
            int c = c0 + ty + r, p = p0 + tx;
            tile[ty + r][tx] = (p < HWP) ? cnn[((size_t)n * CC + c) * HWP + p] : 0.f;
        }
        __syncthreads();
        #pragma unroll
        for (int r = 0; r < 32; r += 8) {
            int p = p0 + ty + r, c = c0 + tx;
            if (p < HWP) {
                __bf16 bv = (__bf16)tile[tx][ty + r];
                cnn_b[((size_t)n * HWP + p) * 128 + c] = bv;
                int y = p / WW, x = p % WW;
                pad_in[(((size_t)n * 47 + y + 1) * 68 + (x + 1)) * 256 + c] = bv;
            }
        }
    } else if (bx < 2720 + 16200) {
        // ---- median pool 8x8: bitonic sort, lane 31 = lower median ----
        int w = (bx - 2720) * 4 + (tid >> 6);
        int lane = tid & 63;
        int n = w / (3 * HWP);
        int rem = w % (3 * HWP);
        int c = rem / HWP;
        int b = rem % HWP;
        const float* src = (c < 2) ? (xy + ((size_t)n * 2 + c) * H0 * W0)
                                   : (orig + ((size_t)n * 4 + 3) * H0 * W0);
        int by = b / WW, bxp = b % WW;
        int r = lane >> 3, col = lane & 7;
        float v = src[(by * 8 + r) * W0 + bxp * 8 + col];
        #pragma unroll
        for (int k = 2; k <= 64; k <<= 1) {
            #pragma unroll
            for (int j2 = k >> 1; j2 >= 1; j2 >>= 1) {
                float p = __shfl_xor(v, j2, 64);
                bool dir = (lane & k) == 0;
                bool low = (lane & j2) == 0;
                v = (dir == low) ? fminf(v, p) : fmaxf(v, p);
            }
        }
        if (lane == 31) proj[(size_t)c * (NB * HWP) + (size_t)n * HWP + b] = v;
    } else if (bx < 2720 + 16200 + 1408) {
        int pb = bx - (2720 + 16200);
        if (pb < 64)        wfrag_body<128>(g_w0, g0f, pb, tid);
        else if (pb < 128)  wfrag_body<128>(g_w1, g1f, pb - 64, tid);
        else if (pb < 256)  wfrag_body<256>(q_w, qf, pb - 128, tid);
        else {
            int t = (pb - 256) * 256 + tid;          // 294,912
            int j = t & 7;
            int lane = (t >> 3) & 63;
            int ntile = (t >> 9) & 7;
            int icc = (t >> 12) & 7;
            int tap = t >> 15;
            int oc = ntile * 16 + (lane & 15);
            int ic = icc * 32 + (lane >> 4) * 8 + j;
            w_frag[t] = (__bf16)conv_w[((size_t)oc * 256 + ic) * 9 + tap];
        }
    } else {
        // ---- zero 496 halo cells per image (all 256 ch) ----
        int t = (bx - (2720 + 16200 + 1408)) * 256 + tid;
        int cg = t & 31;
        int s = t >> 5;
        int cell = s % 496;
        int n = s / 496;
        int y, x;
        if (cell < 136) { y = (cell < 68) ? 0 : 46; x = cell % 68; }
        else {
            int rem = cell - 136;
            y = 1 + rem / 8;
            int k = rem % 8;
            x = (k == 0) ? 0 : (60 + k);
        }
        bf16_8 z = {};
        *(bf16_8*)&pad_in[(((size_t)n * 47 + y) * 68 + x) * 256 + cg * 8] = z;
    }
}

// ---------------------------------------------------------------------------
// 5) bf16 GEMM layer (unchanged)
// ---------------------------------------------------------------------------
__device__ __forceinline__ void layer_b(
    const __bf16* __restrict__ src,                // LDS [32][136] bf16
    const __bf16* __restrict__ wf,                 // global fragments
    int wave, int lane, int kc_base, f32x4 acc[2][2]) {
    int quad = lane >> 4, lm = lane & 15;
    const bf16_8* wf8 = (const bf16_8*)wf;
    #pragma unroll
    for (int kc = 0; kc < 4; ++kc) {
        bf16_8 b[2], a[2];
        #pragma unroll
        for (int nt = 0; nt < 2; ++nt)
            b[nt] = *(const bf16_8*)&src[(nt * 16 + lm) * 136 + kc * 32 + quad * 8];
        #pragma unroll
        for (int mt = 0; mt < 2; ++mt)
            a[mt] = wf8[((size_t)(kc_base + kc) * 8 + (wave * 2 + mt)) * 64 + lane];
        #pragma unroll
        for (int mt = 0; mt < 2; ++mt)
            #pragma unroll
            for (int nt = 0; nt < 2; ++nt)
                acc[mt][nt] = __builtin_amdgcn_mfma_f32_16x16x32_bf16(
                    a[mt], b[nt], acc[mt][nt], 0, 0, 0);
    }
}

// ---------------------------------------------------------------------------
// 3+5a) MERGED: KNN overlapped with g-MLP iter 1. KNN reverted to the
//       round-1 single-row structure (2-row experiment was latency-bound
//       loss: halved wave supply on a DS-pipe-latency-bound kernel).
//       NEW: ballot-based prefix compaction replaces the 43 rounds of
//       same-address LDS atomicAdd (per-lane serialization on the DS pipe).
//       Survivor SET and count are identical; exact (d,idx) sort makes the
//       output independent of slot order -> bit-identical knn indices.
//       LDS: union of knn{pts 43200 + sbufj 2048} and
//       g{2 x (albuf 8704 + inter 8704)} = 45280 B.
//       NOTE: s = fmaf(-2,r,a) is bit-identical to a - 2.0f*r (2r exact).
// ---------------------------------------------------------------------------
#define GBLK 340
__global__ void __launch_bounds__(512, 6) knn_g1(
    const float* __restrict__ proj, int* __restrict__ knn,
    const __bf16* __restrict__ Ain,
    const __bf16* __restrict__ w0f, const float* __restrict__ b0, const float* __restrict__ a0p,
    const __bf16* __restrict__ w1f, const float* __restrict__ b1, const float* __restrict__ a1p,
    __bf16* __restrict__ tgb) {
    __shared__ __align__(16) char smraw[45280];
    int bx = blockIdx.x;
    if (bx >= GBLK) {
        // =================== KNN path (round-1 + ballot compaction) =======
#pragma clang fp contract(off)
        float4* pts = (float4*)smraw;                      // (x,y,z,sq)
        int (*sbufj)[64] = (int(*)[64])(smraw + 43200);
        int kb = bx - GBLK;                                // 0..2703
        int n = kb & 7;
        int chunk = kb >> 3;                               // 0..337
        const float* px = proj + (size_t)n * HWP;
        const float* py = proj + (size_t)NB * HWP + (size_t)n * HWP;
        const float* pz = proj + (size_t)2 * NB * HWP + (size_t)n * HWP;
        for (int t = threadIdx.x; t < HWP; t += 512) {
            float x = px[t], y = py[t], z = pz[t];
            float4 p;
            p.x = x; p.y = y; p.z = z;
            p.w = (x * x + y * y) + z * z;                 // mirrors jnp.sum(proj*proj,-1)
            pts[t] = p;
        }
        __syncthreads();

        int wave = threadIdx.x >> 6;
        int lane = threadIdx.x & 63;
        int i = chunk * 8 + wave;                          // row (338*8 >= 2700)
        if (i >= HWP) return;                              // no syncs after this point
        float4 pi = pts[i];
        float xi = pi.x, yi = pi.y, zi = pi.z, sqi = pi.w;

        // ---- Pass A: squared distances; lane min; packed u16 upper bounds ----
        unsigned int sdp[22];
        float mn = FLT_MAX;
        #pragma unroll
        for (int t = 0; t < NT; ++t) {
            int j = lane + t * 64;
            unsigned int u = 0xFFFFu;
            if (j < HWP) {
                float4 pj = pts[j];
                float r = fmaf(zi, pj.z, fmaf(yi, pj.y, xi * pj.x));
                float s = fmaf(-2.0f, r, sqi + pj.w);
                mn = fminf(mn, s);
                float sc = fmaxf(s, 0.f);
                u = (__float_as_uint(sc) + 0xFFFFu) >> 16;   // >= sc, <= sc*(1+2^-7)
            }
            if (t & 1) sdp[t >> 1] |= (u << 16);
            else       sdp[t >> 1] = u;
        }

        // ---- Bitonic sort the 64 lane minima ascending; M_s = rank 15 ----
        float v = mn;
        #pragma unroll
        for (int k = 2; k <= 64; k <<= 1) {
            #pragma unroll
            for (int j2 = k >> 1; j2 >= 1; j2 >>= 1) {
                float p = __shfl_xor(v, j2, 64);
                bool dir = (lane & k) == 0;
                bool low = (lane & j2) == 0;
                v = (dir == low) ? fminf(v, p) : fmaxf(v, p);
            }
        }
        float M_s = __shfl(v, 15, 64);
        float M_test = (M_s > 0.f) ? (M_s * 1.0000005f + 1e-37f) : 0.0f;
        float M_t2 = M_test * 1.009f;                  // cover u16 round-up slack
        unsigned int M16 = __float_as_uint(M_t2) >> 16;   // u<=M16 <=> (u<<16)<=M_bits

        // ---- Pass B: ballot-prefix compaction (no LDS atomics) ----
        unsigned long long below = (lane == 63) ? 0x7FFFFFFFFFFFFFFFull
                                                : ((1ull << lane) - 1ull);
        int cnt = 0;
        #pragma unroll
        for (int t = 0; t < NT; ++t) {
            unsigned int u = (t & 1) ? (sdp[t >> 1] >> 16) : (sdp[t >> 1] & 0xFFFFu);
            bool pred = (u <= M16);
            unsigned long long mask = __ballot(pred);
            if (pred) {
                int slot = cnt + __popcll(mask & below);
                if (slot < 64) sbufj[wave][slot] = lane + t * 64;
            }
            cnt += (int)__popcll(mask);
        }

        int myj = 0;
        if (cnt >= KNN && cnt <= 64) {
            // ---- exact (d, idx) keys for survivors; 64-wide u64 bitonic sort ----
            unsigned long long key = ~0ull;
            if (lane < cnt) {
                int j = sbufj[wave][lane];
                float4 pj = pts[j];
                float r = fmaf(zi, pj.z, fmaf(yi, pj.y, xi * pj.x));
                float s = fmaf(-2.0f, r, sqi + pj.w);
                float d = sqrtf(fmaxf(s, 0.f));
                key = ((unsigned long long)__float_as_uint(d) << 32) | (unsigned int)j;
            }
            #pragma unroll
            for (int k = 2; k <= 64; k <<= 1) {
                #pragma unroll
                for (int j2 = k >> 1; j2 >= 1; j2 >>= 1) {
                    unsigned long long p = __shfl_xor(key, j2, 64);
                    bool dir = (lane & k) == 0;
                    bool low = (lane & j2) == 0;
                    bool keepmin = (dir == low);
                    bool pless = p < key;
                    key = (pless == keepmin) ? p : key;
                }
            }
            myj = (int)(unsigned int)(key & 0xffffffffull);
        } else {
            // ---- rare fallback: 16 rounds of lex-argmin rescan (low-register) ----
            float lastd = -FLT_MAX; int lastj = -1;
            #pragma unroll 1
            for (int r = 0; r < KNN; ++r) {
                float bd = FLT_MAX; int bj = 0x7fffffff;
                #pragma unroll 1
                for (int t = 0; t < NT; ++t) {
                    int j = lane + t * 64;
                    if (j < HWP) {
                        float4 pj = pts[j];
                        float rr = fmaf(zi, pj.z, fmaf(yi, pj.y, xi * pj.x));
                        float s = fmaf(-2.0f, rr, sqi + pj.w);
                        float d = sqrtf(fmaxf(s, 0.f));
                        bool gt = (d > lastd) || (d == lastd && j > lastj);
                        bool lt = (d < bd) || (d == bd && j < bj);
                        if (gt && lt) { bd = d; bj = j; }
                    }
                }
                float md = bd; int mj = bj;
                #pragma unroll
                for (int off = 32; off >= 1; off >>= 1) {
                    float od = __shfl_xor(md, off, 64);
                    int oj = __shfl_xor(mj, off, 64);
                    if (od < md || (od == md && oj < mj)) { md = od; mj = oj; }
                }
                if (lane == r) myj = mj;
                lastd = md; lastj = mj;
            }
        }
        if (lane < KNN)
            knn[((size_t)n * HWP + i) * KNN + lane] = myj;
    } else {
        // =================== g-MLP iter-1 path (2 virtual 256-thr blocks) ====
        int half = threadIdx.x >> 8;                   // 0..1
        int tid = threadIdx.x & 255;
        int vb = bx * 2 + half;                        // 0..679 (old fused_g bx)
        __bf16* sb = (__bf16*)smraw;
        __bf16* albuf = sb + half * (32 * 136);
        __bf16* inter = sb + (2 + half) * (32 * 136);
        int nimg = vb & 7;
        int r0 = (vb >> 3) * 32;
        size_t base = (size_t)nimg * HWP;
        int wave = tid >> 6, lane = tid & 63;
        int quad = lane >> 4, lm = lane & 15;
        #pragma unroll
        for (int t = tid; t < 512; t += 256) {
            int row = t >> 4, c8 = (t & 15) * 8;
            int gr = r0 + row; if (gr >= HWP) gr = HWP - 1;   // clamped (discarded later)
            *(bf16_8*)&albuf[row * 136 + c8] =
                *(const bf16_8*)&Ain[(base + gr) * 128 + c8];
        }
        __syncthreads();
        // layer 0
        {
            f32x4 acc[2][2] = {};
            layer_b(albuf, w0f, wave, lane, 0, acc);
            float alpha = a0p[0];
            #pragma unroll
            for (int mt = 0; mt < 2; ++mt) {
                int oc0 = wave * 32 + mt * 16 + quad * 4;
                float4 bb = *(const float4*)&b0[oc0];
                float bv[4] = {bb.x, bb.y, bb.z, bb.w};
                #pragma unroll
                for (int nt = 0; nt < 2; ++nt) {
                    bf16_4 o;
                    #pragma unroll
                    for (int reg = 0; reg < 4; ++reg) {
                        float vv = acc[mt][nt][reg] + bv[reg];
                        vv = (vv >= 0.f) ? vv : alpha * vv;
                        o[reg] = (__bf16)vv;
                    }
                    *(bf16_4*)&inter[(nt * 16 + lm) * 136 + oc0] = o;
                }
            }
        }
        __syncthreads();
        // layer 1
        {
            f32x4 acc[2][2] = {};
            layer_b(inter, w1f, wave, lane, 0, acc);
            float alpha = a1p[0];
            #pragma unroll
            for (int mt = 0; mt < 2; ++mt) {
                int oc0 = wave * 32 + mt * 16 + quad * 4;
                float4 bb = *(const float4*)&b1[oc0];
                float bv[4] = {bb.x, bb.y, bb.z, bb.w};
                #pragma unroll
                for (int nt = 0; nt < 2; ++nt) {
                    bf16_4 o;
                    #pragma unroll
                    for (int reg = 0; reg < 4; ++reg) {
                        float vv = acc[mt][nt][reg] + bv[reg];
                        vv = (vv >= 0.f) ? vv : alpha * vv;
                        o[reg] = (__bf16)vv;
                    }
                    int grow = r0 + nt * 16 + lm;
                    if (grow < HWP)
                        *(bf16_4*)&tgb[(base + grow) * 128 + oc0] = o;
                }
            }
        }
    }
}

// ---------------------------------------------------------------------------
// 5b') FUSED q(iter1) + g-MLP(iter2): block b's q output rows 32b..32b+31 are
//      exactly what g(iter2) block b consumes -> keep them in LDS. Writes
//      h_b (for q iter2 Ain) and tgb2 (fresh buffer: gather reads of tgb_in
//      race with in-place writes otherwise). Bit-exact with the old pipeline.
// ---------------------------------------------------------------------------
__global__ void __launch_bounds__(256) fused_qg(
    const __bf16* __restrict__ Ain, const __bf16* __restrict__ tgb_in,
    const int* __restrict__ knn_idx,
    const __bf16* __restrict__ qf, const float* __restrict__ qb, const float* __restrict__ qap,
    const __bf16* __restrict__ w0f, const float* __restrict__ b0, const float* __restrict__ a0p,
    const __bf16* __restrict__ w1f, const float* __restrict__ b1, const float* __restrict__ a1p,
    __bf16* __restrict__ h_out, __bf16* __restrict__ tgb_out) {
    __shared__ __bf16 hlds[32 * 136];
    __shared__ __bf16 mlds[32 * 136];
    int bx = blockIdx.x;
    int nimg = bx & 7;
    int r0 = (bx >> 3) * 32;
    size_t base = (size_t)nimg * HWP;
    int tid = threadIdx.x;
    int wave = tid >> 6, lane = tid & 63;
    int quad = lane >> 4, lm = lane & 15;
    #pragma unroll
    for (int t = tid; t < 512; t += 256) {
        int row = t >> 4, c8 = (t & 15) * 8;
        int gr = r0 + row; if (gr >= HWP) gr = HWP - 1;
        *(bf16_8*)&hlds[row * 136 + c8] =
            *(const bf16_8*)&Ain[(base + gr) * 128 + c8];
    }
    {   // gather + mean: thread handles (pix, 16 channels)
        int pix = tid >> 3;
        int oct0 = (tid & 7) * 2;
        int grow = r0 + pix; if (grow >= HWP) grow = HWP - 1;
        const int* kn = knn_idx + (base + grow) * KNN;
        const __bf16* tbase = tgb_in + base * 128;
        float a0[8] = {}, a1[8] = {};
        #pragma unroll
        for (int k = 0; k < KNN; ++k) {
            int j = kn[k];
            const __bf16* srcp = tbase + (size_t)j * 128 + oct0 * 8;
            bf16_8 v0 = *(const bf16_8*)srcp;
            bf16_8 v1 = *(const bf16_8*)(srcp + 8);
            #pragma unroll
            for (int e = 0; e < 8; ++e) { a0[e] += (float)v0[e]; a1[e] += (float)v1[e]; }
        }
        const float s = 1.f / 16.f;
        bf16_8 o0, o1;
        #pragma unroll
        for (int e = 0; e < 8; ++e) { o0[e] = (__bf16)(a0[e] * s); o1[e] = (__bf16)(a1[e] * s); }
        *(bf16_8*)&mlds[pix * 136 + oct0 * 8] = o0;
        *(bf16_8*)&mlds[pix * 136 + oct0 * 8 + 8] = o1;
    }
    __syncthreads();
    // q-GEMM
    {
        f32x4 acc[2][2] = {};
        layer_b(hlds, qf, wave, lane, 0, acc);   // k 0..127 (h part)
        layer_b(mlds, qf, wave, lane, 4, acc);   // k 128..255 (m part)
        __syncthreads();                         // all LDS reads done before overwrite
        float alpha = qap[0];
        #pragma unroll
        for (int mt = 0; mt < 2; ++mt) {
            int oc0 = wave * 32 + mt * 16 + quad * 4;
            float4 bb = *(const float4*)&qb[oc0];
            float bv[4] = {bb.x, bb.y, bb.z, bb.w};
            #pragma unroll
            for (int nt = 0; nt < 2; ++nt) {
                bf16_4 o;
                #pragma unroll
                for (int reg = 0; reg < 4; ++reg) {
                    float vv = acc[mt][nt][reg] + bv[reg];
                    vv = (vv >= 0.f) ? vv : alpha * vv;
                    o[reg] = (__bf16)vv;
                }
                *(bf16_4*)&hlds[(nt * 16 + lm) * 136 + oc0] = o;   // stays resident
                int grow = r0 + nt * 16 + lm;
                if (grow < HWP)
                    *(bf16_4*)&h_out[(base + grow) * 128 + oc0] = o;
            }
        }
    }
    __syncthreads();
    // g layer 0 (hlds -> mlds)
    {
        f32x4 acc[2][2] = {};
        layer_b(hlds, w0f, wave, lane, 0, acc);
        float alpha = a0p[0];
        #pragma unroll
        for (int mt = 0; mt < 2; ++mt) {
            int oc0 = wave * 32 + mt * 16 + quad * 4;
            float4 bb = *(const float4*)&b0[oc0];
            float bv[4] = {bb.x, bb.y, bb.z, bb.w};
            #pragma unroll
            for (int nt = 0; nt < 2; ++nt) {
                bf16_4 o;
                #pragma unroll
                for (int reg = 0; reg < 4; ++reg) {
                    float vv = acc[mt][nt][reg] + bv[reg];
                    vv = (vv >= 0.f) ? vv : alpha * vv;
                    o[reg] = (__bf16)vv;
                }
                *(bf16_4*)&mlds[(nt * 16 + lm) * 136 + oc0] = o;
            }
        }
    }
    __syncthreads();
    // g layer 1 (mlds -> tgb_out)
    {
        f32x4 acc[2][2] = {};
        layer_b(mlds, w1f, wave, lane, 0, acc);
        float alpha = a1p[0];
        #pragma unroll
        for (int mt = 0; mt < 2; ++mt) {
            int oc0 = wave * 32 + mt * 16 + quad * 4;
            float4 bb = *(const float4*)&b1[oc0];
            float bv[4] = {bb.x, bb.y, bb.z, bb.w};
            #pragma unroll
            for (int nt = 0; nt < 2; ++nt) {
                bf16_4 o;
                #pragma unroll
                for (int reg = 0; reg < 4; ++reg) {
                    float vv = acc[mt][nt][reg] + bv[reg];
                    vv = (vv >= 0.f) ? vv : alpha * vv;
                    o[reg] = (__bf16)vv;
                }
                int grow = r0 + nt * 16 + lm;
                if (grow < HWP)
                    *(bf16_4*)&tgb_out[(base + grow) * 128 + oc0] = o;
            }
        }
    }
}

// ---------------------------------------------------------------------------
// 5b) Fused gather-mean + q-GEMM (iteration 2, scatters into pad_in ch 128..255)
// ---------------------------------------------------------------------------
__global__ void __launch_bounds__(256) fused_q(
    const __bf16* __restrict__ Ain, const __bf16* __restrict__ tgb,
    const int* __restrict__ knn_idx,
    const __bf16* __restrict__ qf, const float* __restrict__ qb,
    const float* __restrict__ qap,
    __bf16* __restrict__ out_lin, __bf16* __restrict__ pad_out, int mode) {
    __shared__ __bf16 hlds[32 * 136];
    __shared__ __bf16 mlds[32 * 136];
    int bx = blockIdx.x;
    int nimg = bx & 7;
    int r0 = (bx >> 3) * 32;
    size_t base = (size_t)nimg * HWP;
    int tid = threadIdx.x;
    int wave = tid >> 6, lane = tid & 63;
    int quad = lane >> 4, lm = lane & 15;
    #pragma unroll
    for (int t = tid; t < 512; t += 256) {
        int row = t >> 4, c8 = (t & 15) * 8;
        int gr = r0 + row; if (gr >= HWP) gr = HWP - 1;
        *(bf16_8*)&hlds[row * 136 + c8] =
            *(const bf16_8*)&Ain[(base + gr) * 128 + c8];
    }
    {   // gather + mean: thread handles (pix, 16 channels)
        int pix = tid >> 3;
        int oct0 = (tid & 7) * 2;
        int grow = r0 + pix; if (grow >= HWP) grow = HWP - 1;
        const int* kn = knn_idx + (base + grow) * KNN;
        const __bf16* tbase = tgb + base * 128;
        float a0[8] = {}, a1[8] = {};
        #pragma unroll
        for (int k = 0; k < KNN; ++k) {
            int j = kn[k];
            const __bf16* srcp = tbase + (size_t)j * 128 + oct0 * 8;
            bf16_8 v0 = *(const bf16_8*)srcp;
            bf16_8 v1 = *(const bf16_8*)(srcp + 8);
            #pragma unroll
            for (int e = 0; e < 8; ++e) { a0[e] += (float)v0[e]; a1[e] += (float)v1[e]; }
        }
        const float s = 1.f / 16.f;
        bf16_8 o0, o1;
        #pragma unroll
        for (int e = 0; e < 8; ++e) { o0[e] = (__bf16)(a0[e] * s); o1[e] = (__bf16)(a1[e] * s); }
        *(bf16_8*)&mlds[pix * 136 + oct0 * 8] = o0;
        *(bf16_8*)&mlds[pix * 136 + oct0 * 8 + 8] = o1;
    }
    __syncthreads();
    f32x4 acc[2][2] = {};
    layer_b(hlds, qf, wave, lane, 0, acc);   // k 0..127 (h part)
    layer_b(mlds, qf, wave, lane, 4, acc);   // k 128..255 (m part)
    float alpha = qap[0];
    #pragma unroll
    for (int mt = 0; mt < 2; ++mt) {
        int oc0 = wave * 32 + mt * 16 + quad * 4;
        float4 bb = *(const float4*)&qb[oc0];
        float bv[4] = {bb.x, bb.y, bb.z, bb.w};
        #pragma unroll
        for (int nt = 0; nt < 2; ++nt) {
            bf16_4 o;
            #pragma unroll
            for (int reg = 0; reg < 4; ++reg) {
                float vv = acc[mt][nt][reg] + bv[reg];
                vv = (vv >= 0.f) ? vv : alpha * vv;
                o[reg] = (__bf16)vv;
            }
            int grow = r0 + nt * 16 + lm;
            if (grow < HWP) {
                if (mode == 0) {
                    *(bf16_4*)&out_lin[(base + grow) * 128 + oc0] = o;
                } else {
                    int y = grow / WW, x = grow % WW;
                    *(bf16_4*)&pad_out[(((size_t)nimg * 47 + y + 1) * 68 + (x + 1)) * 256 + 128 + oc0] = o;
                }
            }
        }
    }
}

// ---------------------------------------------------------------------------
// 6) Conv 3x3 MFMA, XCD-swizzled flat grid (720): image = blockIdx&7.
// ---------------------------------------------------------------------------
__global__ void __launch_bounds__(256) conv_mfma(
    const __bf16* __restrict__ pad_in,   // (N,47,68,256)
    const __bf16* __restrict__ w_frag,   // fragment-ordered weights
    const float* __restrict__ bias,
    float* __restrict__ out) {           // (N,128,45,60)
    __shared__ __bf16 alds[3 * 66 * 72];         // [dy][px 0..65][ic 0..63], stride 72
    int bx = blockIdx.x;
    int n = bx & 7;
    int rest = bx >> 3;                  // 0..89
    int y = rest % HH;
    int oh = rest / HH;
    int tid = threadIdx.x;
    int wave = tid >> 6, lane = tid & 63;
    int wm = wave & 1, wq = wave >> 1;
    int quad = lane >> 4, lm = lane & 15;

    f32x4 acc[2][2] = {};
    const bf16_8* wf = (const bf16_8*)w_frag;

    for (int c64 = 0; c64 < 4; ++c64) {
        __syncthreads();
        for (int t = tid; t < 1584; t += 256) {  // 3*66*8 x 16B
            int cq = t & 7;
            int xp = (t >> 3) % 66;
            int dy = (t >> 3) / 66;
            size_t src = (((size_t)n * 47 + (y + dy)) * 68 + xp) * 256 + c64 * 64 + cq * 8;
            *(bf16_8*)&alds[(dy * 66 + xp) * 72 + cq * 8] = *(const bf16_8*)&pad_in[src];
        }
        __syncthreads();
        #pragma unroll
        for (int tap = 0; tap < 9; ++tap) {
            int ky = tap / 3, kx = tap % 3;
            #pragma unroll
            for (int h = 0; h < 2; ++h) {
                int icc = c64 * 2 + h;
                bf16_8 b[2], a[2];
                #pragma unroll
                for (int nt = 0; nt < 2; ++nt)
                    b[nt] = wf[(((tap * 8 + icc) * 8) + (oh * 4 + wq * 2 + nt)) * 64 + lane];
                #pragma unroll
                for (int mt = 0; mt < 2; ++mt)
                    a[mt] = *(const bf16_8*)&alds[(ky * 66 + (wm * 32 + mt * 16 + lm + kx)) * 72
                                                  + h * 32 + quad * 8];
                #pragma unroll
                for (int mt = 0; mt < 2; ++mt)
                    #pragma unroll
                    for (int nt = 0; nt < 2; ++nt)
                        acc[mt][nt] = __builtin_amdgcn_mfma_f32_16x16x32_bf16(
                            a[mt], b[nt], acc[mt][nt], 0, 0, 0);
            }
        }
    }
    #pragma unroll
    for (int mt = 0; mt < 2; ++mt) {
        int x0 = wm * 32 + mt * 16 + quad * 4;
        if (x0 >= WW) continue;
        #pragma unroll
        for (int nt = 0; nt < 2; ++nt) {
            int oc = (oh * 4 + wq * 2 + nt) * 16 + lm;
            float bb = bias[oc];
            f32x4 v = acc[mt][nt];
            v[0] += bb; v[1] += bb; v[2] += bb; v[3] += bb;
            *(f32x4*)&out[(((size_t)n * 128 + oc) * HH + y) * WW + x0] = v;
        }
    }
}

// ---------------------------------------------------------------------------
extern "C" void kernel_launch(void* const* d_in, const int* in_sizes, int n_in,
                              void* d_out, int out_size, void* d_ws, size_t ws_size,
                              hipStream_t stream) {
    const float* cnn    = (const float*)d_in[0];
    const float* orig   = (const float*)d_in[1];
    const float* xy     = (const float*)d_in[2];
    const float* g_w0   = (const float*)d_in[3];
    const float* g_b0   = (const float*)d_in[4];
    const float* g_a0   = (const float*)d_in[5];
    const float* g_w1   = (const float*)d_in[6];
    const float* g_b1   = (const float*)d_in[7];
    const float* g_a1   = (const float*)d_in[8];
    const float* q_w    = (const float*)d_in[9];
    const float* q_b    = (const float*)d_in[10];
    const float* q_a    = (const float*)d_in[11];
    const float* conv_w = (const float*)d_in[12];
    const float* conv_b = (const float*)d_in[13];
    float* out = (float*)d_out;

    float* ws = (float*)d_ws;
    const size_t SB = (size_t)MROWS * 128;      // bf16 activation plane count
    __bf16* cnn_b  = (__bf16*)ws;               // SB bf16
    __bf16* h_b    = cnn_b + SB;
    __bf16* tgb    = h_b + SB;
    float*  proj   = (float*)(tgb + SB);        // 64,800 fl
    int*    knn_i  = (int*)(proj + 64800);      // 345,600 int
    __bf16* g0f    = (__bf16*)(knn_i + (size_t)MROWS * KNN);
    __bf16* g1f    = g0f + 16384;
    __bf16* qf     = g1f + 16384;               // 32,768 bf16
    __bf16* w_frag = qf + 32768;                // 294,912 bf16
    __bf16* pad_in = w_frag + 294912;           // 6,545,408 bf16
    __bf16* tgb2   = pad_in + (size_t)NB * 47 * 68 * 256;   // SB bf16 (iter-2 tgb)

    setup_all<<<2720 + 16200 + 1408 + 496, 256, 0, stream>>>(
        cnn, xy, orig, g_w0, g_w1, q_w, conv_w,
        cnn_b, pad_in, proj, g0f, g1f, qf, w_frag);

    // KNN (ballot compaction, VALU) overlapped with g-MLP iteration 1 (MFMA)
    knn_g1<<<GBLK + 2704, 512, 0, stream>>>(
        proj, knn_i, cnn_b, g0f, g_b0, g_a0, g1f, g_b1, g_a1, tgb);

    // q iteration 1 fused with g iteration 2 (LDS-resident handoff)
    fused_qg<<<680, 256, 0, stream>>>(
        cnn_b, tgb, knn_i, qf, q_b, q_a,
        g0f, g_b0, g_a0, g1f, g_b1, g_a1, h_b, tgb2);

    // q iteration 2 scatters straight into conv staging
    fused_q<<<680, 256, 0, stream>>>(h_b, tgb2, knn_i, qf, q_b, q_a, h_b, pad_in, 1);

    // Conv epilogue
    conv_mfma<<<720, 256, 0, stream>>>(pad_in, w_frag, conv_b, out);
}

// Round 6
// 222.489 us; speedup vs baseline: 1.1077x; 1.0021x over previous
//
#include <hip/hip_runtime.h>
#include <cfloat>
#include <cmath>

#define NB 8
#define CC 128
#define HH 45
#define WW 60
#define HWP 2700      // H*W
#define KNN 16
#define H0 360
#define W0 480
#define NT 43         // ceil(2700/64) candidates per lane
#define MROWS 21600   // NB * HWP

typedef __bf16 bf16_8 __attribute__((ext_vector_type(8)));
typedef __bf16 bf16_4 __attribute__((ext_vector_type(4)));
typedef float  f32x4  __attribute__((ext_vector_type(4)));

// ---------------------------------------------------------------------------
// 0) Fused setup (only what knn_g1 depends on): transpose+bf16-cast (2720) |
//    median pool (16200) | g0f/g1f weight fragments (128).
//    qf / conv w_frag / halo-zero moved into knn_g1 aux blocks (their
//    consumers run after knn_g1).
// ---------------------------------------------------------------------------
template <int K>
__device__ __forceinline__ void wfrag_body(const float* __restrict__ Wt,
                                           __bf16* __restrict__ wf, int bx, int tid) {
    int t = bx * 256 + tid;
    int j = t & 7;
    int lane = (t >> 3) & 63;
    int nt = (t >> 9) & 7;
    int kc = t >> 12;
    int oc = nt * 16 + (lane & 15);
    int k = kc * 32 + (lane >> 4) * 8 + j;
    wf[t] = (__bf16)Wt[(size_t)oc * K + k];
}

__global__ void __launch_bounds__(256) setup_all(
    const float* __restrict__ cnn, const float* __restrict__ xy,
    const float* __restrict__ orig,
    const float* __restrict__ g_w0, const float* __restrict__ g_w1,
    __bf16* __restrict__ cnn_b, __bf16* __restrict__ pad_in,
    float* __restrict__ proj,
    __bf16* __restrict__ g0f, __bf16* __restrict__ g1f) {
    int bx = blockIdx.x;
    int tid = threadIdx.x;
    if (bx < 2720) {
        // ---- transpose (N,128,HW) -> cnn_b + pad_in ch 0..127 ----
        __shared__ float tile[32][33];
        int n = bx / 340;
        int r2 = bx % 340;
        int c0 = (r2 / 85) * 32;
        int p0 = (r2 % 85) * 32;
        int tx = tid & 31, ty = tid >> 5;
        #pragma unroll
        for (int r = 0; r < 32; r += 8) {
            int c = c0 + ty + r, p = p0 + tx;
            tile[ty + r][tx] = (p < HWP) ? cnn[((size_t)n * CC + c) * HWP + p] : 0.f;
        }
        __syncthreads();
        #pragma unroll
        for (int r = 0; r < 32; r += 8) {
            int p = p0 + ty + r, c = c0 + tx;
            if (p < HWP) {
                __bf16 bv = (__bf16)tile[tx][ty + r];
                cnn_b[((size_t)n * HWP + p) * 128 + c] = bv;
                int y = p / WW, x = p % WW;
                pad_in[(((size_t)n * 47 + y + 1) * 68 + (x + 1)) * 256 + c] = bv;
            }
        }
    } else if (bx < 2720 + 16200) {
        // ---- median pool 8x8: bitonic sort, lane 31 = lower median ----
        int w = (bx - 2720) * 4 + (tid >> 6);
        int lane = tid & 63;
        int n = w / (3 * HWP);
        int rem = w % (3 * HWP);
        int c = rem / HWP;
        int b = rem % HWP;
        const float* src = (c < 2) ? (xy + ((size_t)n * 2 + c) * H0 * W0)
                                   : (orig + ((size_t)n * 4 + 3) * H0 * W0);
        int by = b / WW, bxp = b % WW;
        int r = lane >> 3, col = lane & 7;
        float v = src[(by * 8 + r) * W0 + bxp * 8 + col];
        #pragma unroll
        for (int k = 2; k <= 64; k <<= 1) {
            #pragma unroll
            for (int j2 = k >> 1; j2 >= 1; j2 >>= 1) {
                float p = __shfl_xor(v, j2, 64);
                bool dir = (lane & k) == 0;
                bool low = (lane & j2) == 0;
                v = (dir == low) ? fminf(v, p) : fmaxf(v, p);
            }
        }
        if (lane == 31) proj[(size_t)c * (NB * HWP) + (size_t)n * HWP + b] = v;
    } else {
        // ---- g-MLP weight fragments (needed by knn_g1's g-path) ----
        int pb = bx - (2720 + 16200);               // 0..127
        if (pb < 64) wfrag_body<128>(g_w0, g0f, pb, tid);
        else         wfrag_body<128>(g_w1, g1f, pb - 64, tid);
    }
}

// ---------------------------------------------------------------------------
// 5) bf16 GEMM layer (unchanged)
// ---------------------------------------------------------------------------
__device__ __forceinline__ void layer_b(
    const __bf16* __restrict__ src,                // LDS [32][136] bf16
    const __bf16* __restrict__ wf,                 // global fragments
    int wave, int lane, int kc_base, f32x4 acc[2][2]) {
    int quad = lane >> 4, lm = lane & 15;
    const bf16_8* wf8 = (const bf16_8*)wf;
    #pragma unroll
    for (int kc = 0; kc < 4; ++kc) {
        bf16_8 b[2], a[2];
        #pragma unroll
        for (int nt = 0; nt < 2; ++nt)
            b[nt] = *(const bf16_8*)&src[(nt * 16 + lm) * 136 + kc * 32 + quad * 8];
        #pragma unroll
        for (int mt = 0; mt < 2; ++mt)
            a[mt] = wf8[((size_t)(kc_base + kc) * 8 + (wave * 2 + mt)) * 64 + lane];
        #pragma unroll
        for (int mt = 0; mt < 2; ++mt)
            #pragma unroll
            for (int nt = 0; nt < 2; ++nt)
                acc[mt][nt] = __builtin_amdgcn_mfma_f32_16x16x32_bf16(
                    a[mt], b[nt], acc[mt][nt], 0, 0, 0);
    }
}

// ---------------------------------------------------------------------------
// 3+5a) MERGED kernel, three block classes (each block takes exactly one
//       path; barriers block-uniform):
//       [0, GBLK)           g-MLP iter-1 (2 virtual 256-thr blocks each)
//       [GBLK, GBLK+2704)   KNN, round-1 validated algorithm (atomic
//                           compaction — ballot version measured SLOWER:
//                           55.3 vs 45.2 µs; atomics only pay for the ~2%
//                           surviving candidates)
//       [GBLK+2704, +888)   aux: qf fragments / conv w_frag / halo zero
//                           (outputs consumed only by later kernels;
//                           dispatched last -> backfill knn drain tail)
//       LDS: union of knn{pts 43200 + sbufj 2048 + scnt 32} and
//       g{2 x (albuf 8704 + inter 8704)} = 45280 B.
//       NOTE: s = fmaf(-2,r,a) is bit-identical to a - 2.0f*r (2r exact).
// ---------------------------------------------------------------------------
#define GBLK 340
#define KNNB 2704
#define AUXB 888
__global__ void __launch_bounds__(512, 6) knn_g1(
    const float* __restrict__ proj, int* __restrict__ knn,
    const __bf16* __restrict__ Ain,
    const __bf16* __restrict__ w0f, const float* __restrict__ b0, const float* __restrict__ a0p,
    const __bf16* __restrict__ w1f, const float* __restrict__ b1, const float* __restrict__ a1p,
    __bf16* __restrict__ tgb,
    const float* __restrict__ q_w, const float* __restrict__ conv_w,
    __bf16* __restrict__ qf, __bf16* __restrict__ w_frag,
    __bf16* __restrict__ pad_in) {
    __shared__ __align__(16) char smraw[45280];
    int bx = blockIdx.x;
    if (bx >= GBLK + KNNB) {
        // =================== aux path (no LDS, no barriers) ===============
        int half = threadIdx.x >> 8;                   // 0..1
        int t256 = threadIdx.x & 255;
        int vb = (bx - (GBLK + KNNB)) * 2 + half;      // 0..1775
        if (vb < 128) {
            wfrag_body<256>(q_w, qf, vb, t256);
        } else if (vb < 1280) {
            int t = (vb - 128) * 256 + t256;           // 0..294,911
            int j = t & 7;
            int lane = (t >> 3) & 63;
            int ntile = (t >> 9) & 7;
            int icc = (t >> 12) & 7;
            int tap = t >> 15;
            int oc = ntile * 16 + (lane & 15);
            int ic = icc * 32 + (lane >> 4) * 8 + j;
            w_frag[t] = (__bf16)conv_w[((size_t)oc * 256 + ic) * 9 + tap];
        } else {
            int t = (vb - 1280) * 256 + t256;          // 0..126,975
            int cg = t & 31;
            int s = t >> 5;
            int cell = s % 496;
            int n = s / 496;
            int y, x;
            if (cell < 136) { y = (cell < 68) ? 0 : 46; x = cell % 68; }
            else {
                int rem = cell - 136;
                y = 1 + rem / 8;
                int k = rem % 8;
                x = (k == 0) ? 0 : (60 + k);
            }
            bf16_8 z = {};
            *(bf16_8*)&pad_in[(((size_t)n * 47 + y) * 68 + x) * 256 + cg * 8] = z;
        }
    } else if (bx >= GBLK) {
        // =================== KNN path (round-1 validated) =================
#pragma clang fp contract(off)
        float4* pts = (float4*)smraw;                      // (x,y,z,sq)
        int (*sbufj)[64] = (int(*)[64])(smraw + 43200);
        int* scnt = (int*)(smraw + 43200 + 2048);
        int kb = bx - GBLK;                                // 0..2703
        int n = kb & 7;
        int chunk = kb >> 3;                               // 0..337
        const float* px = proj + (size_t)n * HWP;
        const float* py = proj + (size_t)NB * HWP + (size_t)n * HWP;
        const float* pz = proj + (size_t)2 * NB * HWP + (size_t)n * HWP;
        for (int t = threadIdx.x; t < HWP; t += 512) {
            float x = px[t], y = py[t], z = pz[t];
            float4 p;
            p.x = x; p.y = y; p.z = z;
            p.w = (x * x + y * y) + z * z;                 // mirrors jnp.sum(proj*proj,-1)
            pts[t] = p;
        }
        __syncthreads();

        int wave = threadIdx.x >> 6;
        int lane = threadIdx.x & 63;
        int i = chunk * 8 + wave;                          // row (338*8 >= 2700)
        if (i >= HWP) return;                              // no syncs after this point
        float4 pi = pts[i];
        float xi = pi.x, yi = pi.y, zi = pi.z, sqi = pi.w;

        // ---- Pass A: squared distances; lane min; packed u16 upper bounds ----
        unsigned int sdp[22];
        float mn = FLT_MAX;
        #pragma unroll
        for (int t = 0; t < NT; ++t) {
            int j = lane + t * 64;
            unsigned int u = 0xFFFFu;
            if (j < HWP) {
                float4 pj = pts[j];
                float r = fmaf(zi, pj.z, fmaf(yi, pj.y, xi * pj.x));
                float s = fmaf(-2.0f, r, sqi + pj.w);
                mn = fminf(mn, s);
                float sc = fmaxf(s, 0.f);
                u = (__float_as_uint(sc) + 0xFFFFu) >> 16;   // >= sc, <= sc*(1+2^-7)
            }
            if (t & 1) sdp[t >> 1] |= (u << 16);
            else       sdp[t >> 1] = u;
        }

        // ---- Bitonic sort the 64 lane minima ascending; M_s = rank 15 ----
        float v = mn;
        #pragma unroll
        for (int k = 2; k <= 64; k <<= 1) {
            #pragma unroll
            for (int j2 = k >> 1; j2 >= 1; j2 >>= 1) {
                float p = __shfl_xor(v, j2, 64);
                bool dir = (lane & k) == 0;
                bool low = (lane & j2) == 0;
                v = (dir == low) ? fminf(v, p) : fmaxf(v, p);
            }
        }
        float M_s = __shfl(v, 15, 64);
        float M_test = (M_s > 0.f) ? (M_s * 1.0000005f + 1e-37f) : 0.0f;
        float M_t2 = M_test * 1.009f;                  // cover u16 round-up slack
        unsigned int M16 = __float_as_uint(M_t2) >> 16;   // u<=M16 <=> (u<<16)<=M_bits

        // ---- Pass B: atomic-slot compaction of survivor indices ----
        if (lane == 0) scnt[wave] = 0;
        #pragma unroll
        for (int t = 0; t < NT; ++t) {
            unsigned int u = (t & 1) ? (sdp[t >> 1] >> 16) : (sdp[t >> 1] & 0xFFFFu);
            if (u <= M16) {
                int slot = atomicAdd(&scnt[wave], 1);
                if (slot < 64) sbufj[wave][slot] = lane + t * 64;
            }
        }
        int cnt = scnt[wave];

        int myj = 0;
        if (cnt >= KNN && cnt <= 64) {
            // ---- exact (d, idx) keys for survivors; 64-wide u64 bitonic sort ----
            unsigned long long key = ~0ull;
            if (lane < cnt) {
                int j = sbufj[wave][lane];
                float4 pj = pts[j];
                float r = fmaf(zi, pj.z, fmaf(yi, pj.y, xi * pj.x));
                float s = fmaf(-2.0f, r, sqi + pj.w);
                float d = sqrtf(fmaxf(s, 0.f));
                key = ((unsigned long long)__float_as_uint(d) << 32) | (unsigned int)j;
            }
            #pragma unroll
            for (int k = 2; k <= 64; k <<= 1) {
                #pragma unroll
                for (int j2 = k >> 1; j2 >= 1; j2 >>= 1) {
                    unsigned long long p = __shfl_xor(key, j2, 64);
                    bool dir = (lane & k) == 0;
                    bool low = (lane & j2) == 0;
                    bool keepmin = (dir == low);
                    bool pless = p < key;
                    key = (pless == keepmin) ? p : key;
                }
            }
            myj = (int)(unsigned int)(key & 0xffffffffull);
        } else {
            // ---- rare fallback: 16 rounds of lex-argmin rescan (low-register) ----
            float lastd = -FLT_MAX; int lastj = -1;
            #pragma unroll 1
            for (int r = 0; r < KNN; ++r) {
                float bd = FLT_MAX; int bj = 0x7fffffff;
                #pragma unroll 1
                for (int t = 0; t < NT; ++t) {
                    int j = lane + t * 64;
                    if (j < HWP) {
                        float4 pj = pts[j];
                        float rr = fmaf(zi, pj.z, fmaf(yi, pj.y, xi * pj.x));
                        float s = fmaf(-2.0f, rr, sqi + pj.w);
                        float d = sqrtf(fmaxf(s, 0.f));
                        bool gt = (d > lastd) || (d == lastd && j > lastj);
                        bool lt = (d < bd) || (d == bd && j < bj);
                        if (gt && lt) { bd = d; bj = j; }
                    }
                }
                float md = bd; int mj = bj;
                #pragma unroll
                for (int off = 32; off >= 1; off >>= 1) {
                    float od = __shfl_xor(md, off, 64);
                    int oj = __shfl_xor(mj, off, 64);
                    if (od < md || (od == md && oj < mj)) { md = od; mj = oj; }
                }
                if (lane == r) myj = mj;
                lastd = md; lastj = mj;
            }
        }
        if (lane < KNN)
            knn[((size_t)n * HWP + i) * KNN + lane] = myj;
    } else {
        // =================== g-MLP iter-1 path (2 virtual 256-thr blocks) ====
        int half = threadIdx.x >> 8;                   // 0..1
        int tid = threadIdx.x & 255;
        int vb = bx * 2 + half;                        // 0..679 (old fused_g bx)
        __bf16* sb = (__bf16*)smraw;
        __bf16* albuf = sb + half * (32 * 136);
        __bf16* inter = sb + (2 + half) * (32 * 136);
        int nimg = vb & 7;
        int r0 = (vb >> 3) * 32;
        size_t base = (size_t)nimg * HWP;
        int wave = tid >> 6, lane = tid & 63;
        int quad = lane >> 4, lm = lane & 15;
        #pragma unroll
        for (int t = tid; t < 512; t += 256) {
            int row = t >> 4, c8 = (t & 15) * 8;
            int gr = r0 + row; if (gr >= HWP) gr = HWP - 1;   // clamped (discarded later)
            *(bf16_8*)&albuf[row * 136 + c8] =
                *(const bf16_8*)&Ain[(base + gr) * 128 + c8];
        }
        __syncthreads();
        // layer 0
        {
            f32x4 acc[2][2] = {};
            layer_b(albuf, w0f, wave, lane, 0, acc);
            float alpha = a0p[0];
            #pragma unroll
            for (int mt = 0; mt < 2; ++mt) {
                int oc0 = wave * 32 + mt * 16 + quad * 4;
                float4 bb = *(const float4*)&b0[oc0];
                float bv[4] = {bb.x, bb.y, bb.z, bb.w};
                #pragma unroll
                for (int nt = 0; nt < 2; ++nt) {
                    bf16_4 o;
                    #pragma unroll
                    for (int reg = 0; reg < 4; ++reg) {
                        float vv = acc[mt][nt][reg] + bv[reg];
                        vv = (vv >= 0.f) ? vv : alpha * vv;
                        o[reg] = (__bf16)vv;
                    }
                    *(bf16_4*)&inter[(nt * 16 + lm) * 136 + oc0] = o;
                }
            }
        }
        __syncthreads();
        // layer 1
        {
            f32x4 acc[2][2] = {};
            layer_b(inter, w1f, wave, lane, 0, acc);
            float alpha = a1p[0];
            #pragma unroll
            for (int mt = 0; mt < 2; ++mt) {
                int oc0 = wave * 32 + mt * 16 + quad * 4;
                float4 bb = *(const float4*)&b1[oc0];
                float bv[4] = {bb.x, bb.y, bb.z, bb.w};
                #pragma unroll
                for (int nt = 0; nt < 2; ++nt) {
                    bf16_4 o;
                    #pragma unroll
                    for (int reg = 0; reg < 4; ++reg) {
                        float vv = acc[mt][nt][reg] + bv[reg];
                        vv = (vv >= 0.f) ? vv : alpha * vv;
                        o[reg] = (__bf16)vv;
                    }
                    int grow = r0 + nt * 16 + lm;
                    if (grow < HWP)
                        *(bf16_4*)&tgb[(base + grow) * 128 + oc0] = o;
                }
            }
        }
    }
}

// ---------------------------------------------------------------------------
// 5b') FUSED q(iter1) + g-MLP(iter2): block b's q output rows 32b..32b+31 are
//      exactly what g(iter2) block b consumes -> keep them in LDS. Writes
//      h_b (for q iter2 Ain) and tgb2 (fresh buffer: gather reads of tgb_in
//      race with in-place writes otherwise). Bit-exact with the old pipeline.
// ---------------------------------------------------------------------------
__global__ void __launch_bounds__(256) fused_qg(
    const __bf16* __restrict__ Ain, const __bf16* __restrict__ tgb_in,
    const int* __restrict__ knn_idx,
    const __bf16* __restrict__ qf, const float* __restrict__ qb, const float* __restrict__ qap,
    const __bf16* __restrict__ w0f, const float* __restrict__ b0, const float* __restrict__ a0p,
    const __bf16* __restrict__ w1f, const float* __restrict__ b1, const float* __restrict__ a1p,
    __bf16* __restrict__ h_out, __bf16* __restrict__ tgb_out) {
    __shared__ __bf16 hlds[32 * 136];
    __shared__ __bf16 mlds[32 * 136];
    int bx = blockIdx.x;
    int nimg = bx & 7;
    int r0 = (bx >> 3) * 32;
    size_t base = (size_t)nimg * HWP;
    int tid = threadIdx.x;
    int wave = tid >> 6, lane = tid & 63;
    int quad = lane >> 4, lm = lane & 15;
    #pragma unroll
    for (int t = tid; t < 512; t += 256) {
        int row = t >> 4, c8 = (t & 15) * 8;
        int gr = r0 + row; if (gr >= HWP) gr = HWP - 1;
        *(bf16_8*)&hlds[row * 136 + c8] =
            *(const bf16_8*)&Ain[(base + gr) * 128 + c8];
    }
    {   // gather + mean: thread handles (pix, 16 channels)
        int pix = tid >> 3;
        int oct0 = (tid & 7) * 2;
        int grow = r0 + pix; if (grow >= HWP) grow = HWP - 1;
        const int* kn = knn_idx + (base + grow) * KNN;
        const __bf16* tbase = tgb_in + base * 128;
        float a0[8] = {}, a1[8] = {};
        #pragma unroll
        for (int k = 0; k < KNN; ++k) {
            int j = kn[k];
            const __bf16* srcp = tbase + (size_t)j * 128 + oct0 * 8;
            bf16_8 v0 = *(const bf16_8*)srcp;
            bf16_8 v1 = *(const bf16_8*)(srcp + 8);
            #pragma unroll
            for (int e = 0; e < 8; ++e) { a0[e] += (float)v0[e]; a1[e] += (float)v1[e]; }
        }
        const float s = 1.f / 16.f;
        bf16_8 o0, o1;
        #pragma unroll
        for (int e = 0; e < 8; ++e) { o0[e] = (__bf16)(a0[e] * s); o1[e] = (__bf16)(a1[e] * s); }
        *(bf16_8*)&mlds[pix * 136 + oct0 * 8] = o0;
        *(bf16_8*)&mlds[pix * 136 + oct0 * 8 + 8] = o1;
    }
    __syncthreads();
    // q-GEMM
    {
        f32x4 acc[2][2] = {};
        layer_b(hlds, qf, wave, lane, 0, acc);   // k 0..127 (h part)
        layer_b(mlds, qf, wave, lane, 4, acc);   // k 128..255 (m part)
        __syncthreads();                         // all LDS reads done before overwrite
        float alpha = qap[0];
        #pragma unroll
        for (int mt = 0; mt < 2; ++mt) {
            int oc0 = wave * 32 + mt * 16 + quad * 4;
            float4 bb = *(const float4*)&qb[oc0];
            float bv[4] = {bb.x, bb.y, bb.z, bb.w};
            #pragma unroll
            for (int nt = 0; nt < 2; ++nt) {
                bf16_4 o;
                #pragma unroll
                for (int reg = 0; reg < 4; ++reg) {
                    float vv = acc[mt][nt][reg] + bv[reg];
                    vv = (vv >= 0.f) ? vv : alpha * vv;
                    o[reg] = (__bf16)vv;
                }
                *(bf16_4*)&hlds[(nt * 16 + lm) * 136 + oc0] = o;   // stays resident
                int grow = r0 + nt * 16 + lm;
                if (grow < HWP)
                    *(bf16_4*)&h_out[(base + grow) * 128 + oc0] = o;
            }
        }
    }
    __syncthreads();
    // g layer 0 (hlds -> mlds)
    {
        f32x4 acc[2][2] = {};
        layer_b(hlds, w0f, wave, lane, 0, acc);
        float alpha = a0p[0];
        #pragma unroll
        for (int mt = 0; mt < 2; ++mt) {
            int oc0 = wave * 32 + mt * 16 + quad * 4;
            float4 bb = *(const float4*)&b0[oc0];
            float bv[4] = {bb.x, bb.y, bb.z, bb.w};
            #pragma unroll
            for (int nt = 0; nt < 2; ++nt) {
                bf16_4 o;
                #pragma unroll
                for (int reg = 0; reg < 4; ++reg) {
                    float vv = acc[mt][nt][reg] + bv[reg];
                    vv = (vv >= 0.f) ? vv : alpha * vv;
                    o[reg] = (__bf16)vv;
                }
                *(bf16_4*)&mlds[(nt * 16 + lm) * 136 + oc0] = o;
            }
        }
    }
    __syncthreads();
    // g layer 1 (mlds -> tgb_out)
    {
        f32x4 acc[2][2] = {};
        layer_b(mlds, w1f, wave, lane, 0, acc);
        float alpha = a1p[0];
        #pragma unroll
        for (int mt = 0; mt < 2; ++mt) {
            int oc0 = wave * 32 + mt * 16 + quad * 4;
            float4 bb = *(const float4*)&b1[oc0];
            float bv[4] = {bb.x, bb.y, bb.z, bb.w};
            #pragma unroll
            for (int nt = 0; nt < 2; ++nt) {
                bf16_4 o;
                #pragma unroll
                for (int reg = 0; reg < 4; ++reg) {
                    float vv = acc[mt][nt][reg] + bv[reg];
                    vv = (vv >= 0.f) ? vv : alpha * vv;
                    o[reg] = (__bf16)vv;
                }
                int grow = r0 + nt * 16 + lm;
                if (grow < HWP)
                    *(bf16_4*)&tgb_out[(base + grow) * 128 + oc0] = o;
            }
        }
    }
}

// ---------------------------------------------------------------------------
// 5b) Fused gather-mean + q-GEMM (iteration 2, scatters into pad_in ch 128..255)
// ---------------------------------------------------------------------------
__global__ void __launch_bounds__(256) fused_q(
    const __bf16* __restrict__ Ain, const __bf16* __restrict__ tgb,
    const int* __restrict__ knn_idx,
    const __bf16* __restrict__ qf, const float* __restrict__ qb,
    const float* __restrict__ qap,
    __bf16* __restrict__ out_lin, __bf16* __restrict__ pad_out, int mode) {
    __shared__ __bf16 hlds[32 * 136];
    __shared__ __bf16 mlds[32 * 136];
    int bx = blockIdx.x;
    int nimg = bx & 7;
    int r0 = (bx >> 3) * 32;
    size_t base = (size_t)nimg * HWP;
    int tid = threadIdx.x;
    int wave = tid >> 6, lane = tid & 63;
    int quad = lane >> 4, lm = lane & 15;
    #pragma unroll
    for (int t = tid; t < 512; t += 256) {
        int row = t >> 4, c8 = (t & 15) * 8;
        int gr = r0 + row; if (gr >= HWP) gr = HWP - 1;
        *(bf16_8*)&hlds[row * 136 + c8] =
            *(const bf16_8*)&Ain[(base + gr) * 128 + c8];
    }
    {   // gather + mean: thread handles (pix, 16 channels)
        int pix = tid >> 3;
        int oct0 = (tid & 7) * 2;
        int grow = r0 + pix; if (grow >= HWP) grow = HWP - 1;
        const int* kn = knn_idx + (base + grow) * KNN;
        const __bf16* tbase = tgb + base * 128;
        float a0[8] = {}, a1[8] = {};
        #pragma unroll
        for (int k = 0; k < KNN; ++k) {
            int j = kn[k];
            const __bf16* srcp = tbase + (size_t)j * 128 + oct0 * 8;
            bf16_8 v0 = *(const bf16_8*)srcp;
            bf16_8 v1 = *(const bf16_8*)(srcp + 8);
            #pragma unroll
            for (int e = 0; e < 8; ++e) { a0[e] += (float)v0[e]; a1[e] += (float)v1[e]; }
        }
        const float s = 1.f / 16.f;
        bf16_8 o0, o1;
        #pragma unroll
        for (int e = 0; e < 8; ++e) { o0[e] = (__bf16)(a0[e] * s); o1[e] = (__bf16)(a1[e] * s); }
        *(bf16_8*)&mlds[pix * 136 + oct0 * 8] = o0;
        *(bf16_8*)&mlds[pix * 136 + oct0 * 8 + 8] = o1;
    }
    __syncthreads();
    f32x4 acc[2][2] = {};
    layer_b(hlds, qf, wave, lane, 0, acc);   // k 0..127 (h part)
    layer_b(mlds, qf, wave, lane, 4, acc);   // k 128..255 (m part)
    float alpha = qap[0];
    #pragma unroll
    for (int mt = 0; mt < 2; ++mt) {
        int oc0 = wave * 32 + mt * 16 + quad * 4;
        float4 bb = *(const float4*)&qb[oc0];
        float bv[4] = {bb.x, bb.y, bb.z, bb.w};
        #pragma unroll
        for (int nt = 0; nt < 2; ++nt) {
            bf16_4 o;
            #pragma unroll
            for (int reg = 0; reg < 4; ++reg) {
                float vv = acc[mt][nt][reg] + bv[reg];
                vv = (vv >= 0.f) ? vv : alpha * vv;
                o[reg] = (__bf16)vv;
            }
            int grow = r0 + nt * 16 + lm;
            if (grow < HWP) {
                if (mode == 0) {
                    *(bf16_4*)&out_lin[(base + grow) * 128 + oc0] = o;
                } else {
                    int y = grow / WW, x = grow % WW;
                    *(bf16_4*)&pad_out[(((size_t)nimg * 47 + y + 1) * 68 + (x + 1)) * 256 + 128 + oc0] = o;
                }
            }
        }
    }
}

// ---------------------------------------------------------------------------
// 6) Conv 3x3 MFMA, XCD-swizzled flat grid (720): image = blockIdx&7.
// ---------------------------------------------------------------------------
__global__ void __launch_bounds__(256) conv_mfma(
    const __bf16* __restrict__ pad_in,   // (N,47,68,256)
    const __bf16* __restrict__ w_frag,   // fragment-ordered weights
    const float* __restrict__ bias,
    float* __restrict__ out) {           // (N,128,45,60)
    __shared__ __bf16 alds[3 * 66 * 72];         // [dy][px 0..65][ic 0..63], stride 72
    int bx = blockIdx.x;
    int n = bx & 7;
    int rest = bx >> 3;                  // 0..89
    int y = rest % HH;
    int oh = rest / HH;
    int tid = threadIdx.x;
    int wave = tid >> 6, lane = tid & 63;
    int wm = wave & 1, wq = wave >> 1;
    int quad = lane >> 4, lm = lane & 15;

    f32x4 acc[2][2] = {};
    const bf16_8* wf = (const bf16_8*)w_frag;

    for (int c64 = 0; c64 < 4; ++c64) {
        __syncthreads();
        for (int t = tid; t < 1584; t += 256) {  // 3*66*8 x 16B
            int cq = t & 7;
            int xp = (t >> 3) % 66;
            int dy = (t >> 3) / 66;
            size_t src = (((size_t)n * 47 + (y + dy)) * 68 + xp) * 256 + c64 * 64 + cq * 8;
            *(bf16_8*)&alds[(dy * 66 + xp) * 72 + cq * 8] = *(const bf16_8*)&pad_in[src];
        }
        __syncthreads();
        #pragma unroll
        for (int tap = 0; tap < 9; ++tap) {
            int ky = tap / 3, kx = tap % 3;
            #pragma unroll
            for (int h = 0; h < 2; ++h) {
                int icc = c64 * 2 + h;
                bf16_8 b[2], a[2];
                #pragma unroll
                for (int nt = 0; nt < 2; ++nt)
                    b[nt] = wf[(((tap * 8 + icc) * 8) + (oh * 4 + wq * 2 + nt)) * 64 + lane];
                #pragma unroll
                for (int mt = 0; mt < 2; ++mt)
                    a[mt] = *(const bf16_8*)&alds[(ky * 66 + (wm * 32 + mt * 16 + lm + kx)) * 72
                                                  + h * 32 + quad * 8];
                #pragma unroll
                for (int mt = 0; mt < 2; ++mt)
                    #pragma unroll
                    for (int nt = 0; nt < 2; ++nt)
                        acc[mt][nt] = __builtin_amdgcn_mfma_f32_16x16x32_bf16(
                            a[mt], b[nt], acc[mt][nt], 0, 0, 0);
            }
        }
    }
    #pragma unroll
    for (int mt = 0; mt < 2; ++mt) {
        int x0 = wm * 32 + mt * 16 + quad * 4;
        if (x0 >= WW) continue;
        #pragma unroll
        for (int nt = 0; nt < 2; ++nt) {
            int oc = (oh * 4 + wq * 2 + nt) * 16 + lm;
            float bb = bias[oc];
            f32x4 v = acc[mt][nt];
            v[0] += bb; v[1] += bb; v[2] += bb; v[3] += bb;
            *(f32x4*)&out[(((size_t)n * 128 + oc) * HH + y) * WW + x0] = v;
        }
    }
}

// ---------------------------------------------------------------------------
extern "C" void kernel_launch(void* const* d_in, const int* in_sizes, int n_in,
                              void* d_out, int out_size, void* d_ws, size_t ws_size,
                              hipStream_t stream) {
    const float* cnn    = (const float*)d_in[0];
    const float* orig   = (const float*)d_in[1];
    const float* xy     = (const float*)d_in[2];
    const float* g_w0   = (const float*)d_in[3];
    const float* g_b0   = (const float*)d_in[4];
    const float* g_a0   = (const float*)d_in[5];
    const float* g_w1   = (const float*)d_in[6];
    const float* g_b1   = (const float*)d_in[7];
    const float* g_a1   = (const float*)d_in[8];
    const float* q_w    = (const float*)d_in[9];
    const float* q_b    = (const float*)d_in[10];
    const float* q_a    = (const float*)d_in[11];
    const float* conv_w = (const float*)d_in[12];
    const float* conv_b = (const float*)d_in[13];
    float* out = (float*)d_out;

    float* ws = (float*)d_ws;
    const size_t SB = (size_t)MROWS * 128;      // bf16 activation plane count
    __bf16* cnn_b  = (__bf16*)ws;               // SB bf16
    __bf16* h_b    = cnn_b + SB;
    __bf16* tgb    = h_b + SB;
    float*  proj   = (float*)(tgb + SB);        // 64,800 fl
    int*    knn_i  = (int*)(proj + 64800);      // 345,600 int
    __bf16* g0f    = (__bf16*)(knn_i + (size_t)MROWS * KNN);
    __bf16* g1f    = g0f + 16384;
    __bf16* qf     = g1f + 16384;               // 32,768 bf16
    __bf16* w_frag = qf + 32768;                // 294,912 bf16
    __bf16* pad_in = w_frag + 294912;           // 6,545,408 bf16
    __bf16* tgb2   = pad_in + (size_t)NB * 47 * 68 * 256;   // SB bf16 (iter-2 tgb)

    // Setup: only the parts knn_g1 depends on (transpose, median pool, g-frags)
    setup_all<<<2720 + 16200 + 128, 256, 0, stream>>>(
        cnn, xy, orig, g_w0, g_w1,
        cnn_b, pad_in, proj, g0f, g1f);

    // KNN (atomic compaction) overlapped with g-MLP iter 1 + aux prep
    knn_g1<<<GBLK + KNNB + AUXB, 512, 0, stream>>>(
        proj, knn_i, cnn_b, g0f, g_b0, g_a0, g1f, g_b1, g_a1, tgb,
        q_w, conv_w, qf, w_frag, pad_in);

    // q iteration 1 fused with g iteration 2 (LDS-resident handoff)
    fused_qg<<<680, 256, 0, stream>>>(
        cnn_b, tgb, knn_i, qf, q_b, q_a,
        g0f, g_b0, g_a0, g1f, g_b1, g_a1, h_b, tgb2);

    // q iteration 2 scatters straight into conv staging
    fused_q<<<680, 256, 0, stream>>>(h_b, tgb2, knn_i, qf, q_b, q_a, h_b, pad_in, 1);

    // Conv epilogue
    conv_mfma<<<720, 256, 0, stream>>>(pad_in, w_frag, conv_b, out);
}